// Round 14
// baseline (2775.646 us; speedup 1.0000x reference)
//
#include <hip/hip_runtime.h>
#include <hip/hip_bf16.h>

// Model constants
#define TT 512
#define NN 1024
#define NH 16
#define HD 64
#define NL 12
#define VV 50257

typedef unsigned short u16;
typedef short bf16x8 __attribute__((ext_vector_type(8)));
typedef float f32x4 __attribute__((ext_vector_type(4)));

__device__ __forceinline__ float gelu_f(float x) {
    float x3 = x * x * x;
    return 0.5f * x * (1.0f + tanhf(0.7978845608028654f * (x + 0.044715f * x3)));
}

// fp32 -> bf16 RNE (finite inputs only)
__device__ __forceinline__ u16 f2b(float f) {
    unsigned int u = __float_as_uint(f);
    return (u16)((u + 0x7FFFu + ((u >> 16) & 1u)) >> 16);
}

// async global->LDS, 16B per lane; LDS dest is wave-uniform base + lane*16
__device__ __forceinline__ void gload16(const void* g, void* l) {
    __builtin_amdgcn_global_load_lds(
        (const __attribute__((address_space(1))) unsigned int*)g,
        (__attribute__((address_space(3))) unsigned int*)l,
        16, 0, 0);
}

// Grid barrier, sense via generation counter. bar[0]=cnt, bar[1]=gen.
// Safe only when ALL blocks of the grid are co-resident (capacity-checked).
__device__ __forceinline__ void gridbar(unsigned* bar, int nblk) {
    __syncthreads();
    if (threadIdx.x == 0) {
        __threadfence();
        unsigned g = __hip_atomic_load(bar + 1, __ATOMIC_ACQUIRE, __HIP_MEMORY_SCOPE_AGENT);
        unsigned a = __hip_atomic_fetch_add(bar, 1u, __ATOMIC_ACQ_REL, __HIP_MEMORY_SCOPE_AGENT);
        if (a == (unsigned)nblk - 1) {
            __hip_atomic_store(bar, 0u, __ATOMIC_RELAXED, __HIP_MEMORY_SCOPE_AGENT);
            __hip_atomic_fetch_add(bar + 1, 1u, __ATOMIC_ACQ_REL, __HIP_MEMORY_SCOPE_AGENT);
        } else {
            while (__hip_atomic_load(bar + 1, __ATOMIC_ACQUIRE, __HIP_MEMORY_SCOPE_AGENT) == g)
                __builtin_amdgcn_s_sleep(2);
        }
        __threadfence();
    }
    __syncthreads();
}

// x[row,:] = 1024*emb[tok[row],:] + 32*pos[t,:]
__global__ __launch_bounds__(256) void embed_k(const int* __restrict__ tok,
        const float* __restrict__ emb, const float* __restrict__ pos,
        float* __restrict__ x) {
    int row = blockIdx.x;
    int t = row & (TT - 1);
    int tk = tok[row];
    int c = threadIdx.x * 4;
    float4 e = *reinterpret_cast<const float4*>(emb + (size_t)tk * NN + c);
    float4 p = *reinterpret_cast<const float4*>(pos + (size_t)t * NN + c);
    float4 o;
    o.x = 1024.f * e.x + 32.f * p.x;
    o.y = 1024.f * e.y + 32.f * p.y;
    o.z = 1024.f * e.z + 32.f * p.z;
    o.w = 1024.f * e.w + 32.f * p.w;
    *reinterpret_cast<float4*>(x + (size_t)row * NN + c) = o;
}

// Row LayerNorm over N=1024 (+ optional gelu), bf16 output
template<int ACT>
__global__ __launch_bounds__(256) void ln_k(const float* __restrict__ in,
        u16* __restrict__ out, const float* __restrict__ sc, const float* __restrict__ bi) {
    int row = blockIdx.x;
    const float* r = in + (size_t)row * NN;
    int tid = threadIdx.x;
    float v[4]; float s1 = 0.f, s2 = 0.f;
    #pragma unroll
    for (int i = 0; i < 4; ++i) { v[i] = r[tid + i * 256]; s1 += v[i]; s2 += v[i] * v[i]; }
    #pragma unroll
    for (int off = 32; off > 0; off >>= 1) { s1 += __shfl_xor(s1, off); s2 += __shfl_xor(s2, off); }
    __shared__ float red[8];
    __shared__ float st[2];
    int wid = tid >> 6;
    if ((tid & 63) == 0) { red[wid] = s1; red[4 + wid] = s2; }
    __syncthreads();
    if (tid == 0) {
        float a = red[0] + red[1] + red[2] + red[3];
        float b = red[4] + red[5] + red[6] + red[7];
        float mu = a * (1.f / NN);
        float var = b * (1.f / NN) - mu * mu;
        st[0] = mu; st[1] = rsqrtf(var + 1e-6f);
    }
    __syncthreads();
    float mu = st[0], rs = st[1];
    u16* o = out + (size_t)row * NN;
    #pragma unroll
    for (int i = 0; i < 4; ++i) {
        int c = tid + i * 256;
        float y = (v[i] - mu) * rs * sc[c] + bi[c];
        if (ACT) y = gelu_f(y);
        o[c] = f2b(y);
    }
}

// Per-layer weight transpose: z (+5*l0) selects (layer, which of 5 matrices).
// fp32 [1024][Ncols] -> bf16 [Ncols][1024] at Wt + l*lstride + doff.
__global__ __launch_bounds__(256) void transpose5_k(const float* __restrict__ qkW,
        const float* __restrict__ vW, const float* __restrict__ oW,
        const float* __restrict__ W1, const float* __restrict__ W2,
        u16* __restrict__ Wt, int l0, size_t lstride) {
    int z = blockIdx.z + l0 * 5;
    int l = z / 5, which = z - l * 5;
    const float* W; int Ncols; size_t doff;
    switch (which) {
      case 0:  W = qkW + (size_t)l * NN * 2048; Ncols = 2048; doff = 0; break;
      case 1:  W = vW + (size_t)l * NN * NN;  Ncols = 1024; doff = (size_t)2048 * 1024; break;
      case 2:  W = oW + (size_t)l * NN * NN;  Ncols = 1024; doff = (size_t)3072 * 1024; break;
      case 3:  W = W1 + (size_t)l * NN * NN;  Ncols = 1024; doff = (size_t)4096 * 1024; break;
      default: W = W2 + (size_t)l * NN * NN;  Ncols = 1024; doff = (size_t)5120 * 1024; break;
    }
    int n0 = blockIdx.x * 64;
    if (n0 >= Ncols) return;
    int k0 = blockIdx.y * 64;
    u16* dst = Wt + (size_t)l * lstride + doff;
    __shared__ float t[64][65];
    int tid = threadIdx.x;
    #pragma unroll
    for (int j = 0; j < 4; ++j) {
        int e = tid + j * 256;
        int kr = e >> 4, nc = (e & 15) * 4;
        float4 v = *reinterpret_cast<const float4*>(W + (size_t)(k0 + kr) * Ncols + n0 + nc);
        t[kr][nc + 0] = v.x; t[kr][nc + 1] = v.y; t[kr][nc + 2] = v.z; t[kr][nc + 3] = v.w;
    }
    __syncthreads();
    #pragma unroll
    for (int j = 0; j < 4; ++j) {
        int e = tid + j * 256;
        int nr = e >> 4, kc = (e & 15) * 4;
        ushort4 o;
        o.x = f2b(t[kc + 0][nr]);
        o.y = f2b(t[kc + 1][nr]);
        o.z = f2b(t[kc + 2][nr]);
        o.w = f2b(t[kc + 3][nr]);
        *reinterpret_cast<ushort4*>(dst + (size_t)(n0 + nr) * 1024 + k0 + kc) = o;
    }
}

// Guarded single transpose (outW): fp32 [K][Ncols] ld=ldW -> bf16 [Npad][K]
__global__ __launch_bounds__(256) void transpose_k(const float* __restrict__ W,
        u16* __restrict__ Wt, int Ncols, int ldW, int K) {
    __shared__ float t[64][65];
    int n0 = blockIdx.x * 64, k0 = blockIdx.y * 64;
    int tid = threadIdx.x;
    #pragma unroll
    for (int j = 0; j < 4; ++j) {
        int e = tid + j * 256;
        int kr = e >> 4, nc = (e & 15) * 4;
        int n = n0 + nc;
        float4 v = {0.f, 0.f, 0.f, 0.f};
        if (n + 3 < Ncols) {
            v = *reinterpret_cast<const float4*>(W + (size_t)(k0 + kr) * ldW + n);
        } else {
            if (n + 0 < Ncols) v.x = W[(size_t)(k0 + kr) * ldW + n + 0];
            if (n + 1 < Ncols) v.y = W[(size_t)(k0 + kr) * ldW + n + 1];
            if (n + 2 < Ncols) v.z = W[(size_t)(k0 + kr) * ldW + n + 2];
        }
        t[kr][nc + 0] = v.x; t[kr][nc + 1] = v.y; t[kr][nc + 2] = v.z; t[kr][nc + 3] = v.w;
    }
    __syncthreads();
    #pragma unroll
    for (int j = 0; j < 4; ++j) {
        int e = tid + j * 256;
        int nr = e >> 4, kc = (e & 15) * 4;
        ushort4 o;
        o.x = f2b(t[kc + 0][nr]);
        o.y = f2b(t[kc + 1][nr]);
        o.z = f2b(t[kc + 2][nr]);
        o.w = f2b(t[kc + 3][nr]);
        *reinterpret_cast<ushort4*>(Wt + (size_t)(n0 + nr) * K + k0 + kc) = o;
    }
}

// swizzled LDS fragment read: row r, logical 16B chunk c
__device__ __forceinline__ bf16x8 ldsfrag(const u16* base, int r, int c) {
    int off = r * 64 + ((c ^ (r & 7)) << 3);
    return *reinterpret_cast<const bf16x8*>(base + off);
}

// MFMA GEMM, TMxTN tile, BK=64, SINGLE-buffer LDS (m97 structure).
// XCDMAP=1: 1D grid (8*k); all 8 m-tiles of a B-panel on the SAME XCD.
// LNF=1: grid-stride LayerNorm+gelu prologue (lnin fp32 -> lnout bf16) followed
//        by a device-scope grid barrier; grid must be fully co-resident
//        (768 blocks @20KB LDS = 3/CU, 512 @16KB = 2/CU: capacity-checked).
// EPI 1: fp32 C += rbeta*(acc*scale)
// EPI 2: bf16 C = gelu(acc*scale)
// EPI 3: fp32 C[row*ldC+coff+n] = (acc+bias)*scale, guarded coff+n<cmax
// EPI 5: fused QKV: n0<2048 -> per-head LN -> qh(C2)/kh(C3); else V^T -> vt(C)
template<int TM, int TN, int EPI, int XCDMAP = 0, int LNF = 0>
__global__ __launch_bounds__(256) void gemm_k(const u16* __restrict__ A,
        const u16* __restrict__ Bt, void* __restrict__ C,
        void* __restrict__ C2, void* __restrict__ C3,
        const float* __restrict__ bias,
        const float* __restrict__ qs, const float* __restrict__ qb,
        const float* __restrict__ ks, const float* __restrict__ kb,
        int K, int ldC, int coff, int cmax, float scale, float rbeta,
        const float* __restrict__ lnin, const float* __restrict__ lnsc,
        const float* __restrict__ lnbi, u16* __restrict__ lnout,
        unsigned* __restrict__ bar) {
    constexpr int MF = TM / 32, NF = TN / 32;     // frags per wave
    constexpr int IA = TM / 8, IB = TN / 8;       // 1KB staging issues
    __shared__ __align__(16) u16 As[TM * 64];
    __shared__ __align__(16) u16 Bs[TN * 64];
    int tid = threadIdx.x;
    int lam = tid & 63, w = tid >> 6;

    if (LNF) {
        // LayerNorm(+gelu) prologue, grid-strided over 1024 rows, then grid barrier
        __shared__ float red[8];
        __shared__ float st[2];
        int nb = gridDim.x * gridDim.y;
        int fb = blockIdx.y * gridDim.x + blockIdx.x;
        for (int row = fb; row < 1024; row += nb) {
            const float* r = lnin + (size_t)row * NN;
            float v[4]; float s1 = 0.f, s2 = 0.f;
            #pragma unroll
            for (int i = 0; i < 4; ++i) { v[i] = r[tid + i * 256]; s1 += v[i]; s2 += v[i] * v[i]; }
            #pragma unroll
            for (int off = 32; off > 0; off >>= 1) { s1 += __shfl_xor(s1, off); s2 += __shfl_xor(s2, off); }
            int wid = tid >> 6;
            if ((tid & 63) == 0) { red[wid] = s1; red[4 + wid] = s2; }
            __syncthreads();
            if (tid == 0) {
                float a = red[0] + red[1] + red[2] + red[3];
                float b = red[4] + red[5] + red[6] + red[7];
                float mu = a * (1.f / NN);
                float var = b * (1.f / NN) - mu * mu;
                st[0] = mu; st[1] = rsqrtf(var + 1e-6f);
            }
            __syncthreads();
            float mu = st[0], rs = st[1];
            u16* o = lnout + (size_t)row * NN;
            #pragma unroll
            for (int i = 0; i < 4; ++i) {
                int c = tid + i * 256;
                o[c] = f2b(gelu_f((v[i] - mu) * rs * lnsc[c] + lnbi[c]));
            }
            __syncthreads();
        }
        gridbar(bar, gridDim.x * gridDim.y);
    }

    int m0, n0;
    if (XCDMAP) {
        int i = blockIdx.x;
        int per = gridDim.x >> 3;          // jobs per XCD
        int j = (i & 7) * per + (i >> 3);  // xcd-grouped job id
        m0 = (j & 7) * TM;                 // 8 m-tiles cycle fastest
        n0 = (j >> 3) * TN;                // consecutive panels per XCD
    } else {
        m0 = blockIdx.y * TM;
        n0 = blockIdx.x * TN;
    }
    int lr = lam >> 3;              // row-in-8 within a 1KB issue
    int lc = (lam & 7) ^ lr;        // inverse-swizzled logical chunk
    const u16* Abase = A + (size_t)m0 * K;
    const u16* Bbase = Bt + (size_t)n0 * K;
    int wr = (w >> 1) * (TM / 2), wc = (w & 1) * (TN / 2);
    int fr = lam & 15, fg = lam >> 4;
    f32x4 acc[MF][NF];
    #pragma unroll
    for (int i = 0; i < MF; ++i)
        #pragma unroll
        for (int j = 0; j < NF; ++j) acc[i][j] = (f32x4)0.0f;

    for (int k0 = 0; k0 < K; k0 += 64) {
        #pragma unroll
        for (int i = 0; i < IA / 4; ++i) {
            int q = w * (IA / 4) + i;
            int r = q * 8 + lr;
            gload16(Abase + (size_t)r * K + k0 + lc * 8, (char*)As + q * 1024);
        }
        #pragma unroll
        for (int i = 0; i < IB / 4; ++i) {
            int q = w * (IB / 4) + i;
            int r = q * 8 + lr;
            gload16(Bbase + (size_t)r * K + k0 + lc * 8, (char*)Bs + q * 1024);
        }
        __syncthreads();                   // drains vmcnt(0) + barrier
        #pragma unroll
        for (int s = 0; s < 2; ++s) {
            bf16x8 af[MF], bfv[NF];
            #pragma unroll
            for (int m = 0; m < MF; ++m) af[m] = ldsfrag(As, wr + m * 16 + fr, s * 4 + fg);
            #pragma unroll
            for (int n = 0; n < NF; ++n) bfv[n] = ldsfrag(Bs, wc + n * 16 + fr, s * 4 + fg);
            #pragma unroll
            for (int m = 0; m < MF; ++m)
                #pragma unroll
                for (int n = 0; n < NF; ++n)
                    acc[m][n] = __builtin_amdgcn_mfma_f32_16x16x32_bf16(af[m], bfv[n], acc[m][n], 0, 0, 0);
        }
        if (k0 + 64 < K) __syncthreads();  // protect LDS overwrite
    }

    // C/D layout: col = lane&15, row = (lane>>4)*4 + reg
    if (EPI == 5) {
        if (n0 < 2048) {
            int sq = wc >> 6;                    // 0 = q half, 1 = k half
            int head = n0 >> 7;
            const float* scp = sq ? ks : qs;
            const float* bip = sq ? kb : qb;
            u16* dst = (u16*)(sq ? C3 : C2);
            float scv[NF], biv[NF];
            #pragma unroll
            for (int n = 0; n < NF; ++n) { scv[n] = scp[n * 16 + fr]; biv[n] = bip[n * 16 + fr]; }
            #pragma unroll
            for (int m = 0; m < MF; ++m) {
                #pragma unroll
                for (int reg = 0; reg < 4; ++reg) {
                    float v[NF]; float s1 = 0.f, s2 = 0.f;
                    #pragma unroll
                    for (int n = 0; n < NF; ++n) {
                        v[n] = acc[m][n][reg] * scale;
                        s1 += v[n]; s2 += v[n] * v[n];
                    }
                    #pragma unroll
                    for (int off = 1; off < 16; off <<= 1) {
                        s1 += __shfl_xor(s1, off);
                        s2 += __shfl_xor(s2, off);
                    }
                    float mu = s1 * (1.f / 64.f);
                    float var = s2 * (1.f / 64.f) - mu * mu;
                    float rs = rsqrtf(var + 1e-6f);
                    int row = m0 + wr + m * 16 + 4 * fg + reg;
                    int bb = row >> 9, t = row & (TT - 1);
                    size_t base = ((size_t)(bb * NH + head) * TT + t) * HD;
                    #pragma unroll
                    for (int n = 0; n < NF; ++n)
                        dst[base + n * 16 + fr] = f2b((v[n] - mu) * rs * scv[n] + biv[n]);
                }
            }
        } else {
            #pragma unroll
            for (int m = 0; m < MF; ++m) {
                int row0 = m0 + wr + m * 16 + 4 * fg;
                int bb = row0 >> 9, t0 = row0 & (TT - 1);
                #pragma unroll
                for (int n = 0; n < NF; ++n) {
                    int colv = n0 - 2048 + wc + n * 16 + fr;
                    int hh = colv >> 6, dd = colv & 63;
                    ushort4 o4;
                    o4.x = f2b(acc[m][n][0] * scale);
                    o4.y = f2b(acc[m][n][1] * scale);
                    o4.z = f2b(acc[m][n][2] * scale);
                    o4.w = f2b(acc[m][n][3] * scale);
                    *reinterpret_cast<ushort4*>((u16*)C +
                        (((size_t)(bb * NH + hh) * HD + dd) * TT + t0)) = o4;
                }
            }
        }
        return;
    }
    #pragma unroll
    for (int m = 0; m < MF; ++m) {
        #pragma unroll
        for (int n = 0; n < NF; ++n) {
            int ncol = n0 + wc + n * 16 + fr;
            int mrow = m0 + wr + m * 16 + 4 * fg;
            #pragma unroll
            for (int reg = 0; reg < 4; ++reg) {
                int row = mrow + reg;
                float v = acc[m][n][reg];
                if (EPI == 1) {
                    float* p = (float*)C + (size_t)row * ldC + ncol;
                    *p = *p + rbeta * (v * scale);
                } else if (EPI == 2) {
                    ((u16*)C)[(size_t)row * ldC + ncol] = f2b(gelu_f(v * scale));
                } else {
                    int gc = coff + ncol;
                    if (gc < cmax)
                        ((float*)C)[(size_t)row * ldC + gc] = (v + bias[gc]) * scale;
                }
            }
        }
    }
}

// Fused flash attention, k-split: per (qt, bh) block, 8 waves (512 thr).
// Wave (sub, half): sub = q-subtile (16 rows), half = kt parity. Both halves
// accumulate unnormalized partial sums (no max-sub => split-K is exact);
// combine via LDS, then normalize.
__global__ __launch_bounds__(512) void attn_k(const u16* __restrict__ qh,
        const u16* __restrict__ kh, const u16* __restrict__ vt,
        u16* __restrict__ ob) {
    int qt = blockIdx.x, bh = blockIdx.y;
    int b = bh >> 4, hh = bh & 15;
    int tid = threadIdx.x;
    int w = tid >> 6, lam = tid & 63;
    int sub = w & 3, half = w >> 2;
    int fr = lam & 15, fg = lam >> 4;
    __shared__ __align__(16) u16 ps[8][16 * 64];   // per-wave P tile, XOR-swizzled
    __shared__ __align__(16) f32x4 comb[4][64][5]; // half-0 partials: oacc[4] + rsum
    u16* pw = ps[w];
    const u16* qbase = qh + ((size_t)bh * TT + qt * 64 + sub * 16) * HD;
    bf16x8 af0 = *reinterpret_cast<const bf16x8*>(qbase + (size_t)fr * HD + fg * 8);
    bf16x8 af1 = *reinterpret_cast<const bf16x8*>(qbase + (size_t)fr * HD + 32 + fg * 8);
    f32x4 oacc[4];
    #pragma unroll
    for (int n = 0; n < 4; ++n) oacc[n] = (f32x4)0.0f;
    float rsum[4] = {0.f, 0.f, 0.f, 0.f};
    const u16* vbh = vt + (size_t)bh * HD * TT;
    for (int kt = half; kt <= qt; kt += 2) {
        const u16* kbase = kh + ((size_t)bh * TT + kt * 64) * HD;
        bool diag = (kt == qt);
        #pragma unroll
        for (int n = 0; n < 4; ++n) {
            bf16x8 b0 = *reinterpret_cast<const bf16x8*>(kbase + (size_t)(n * 16 + fr) * HD + fg * 8);
            bf16x8 b1 = *reinterpret_cast<const bf16x8*>(kbase + (size_t)(n * 16 + fr) * HD + 32 + fg * 8);
            f32x4 s = (f32x4)0.0f;
            s = __builtin_amdgcn_mfma_f32_16x16x32_bf16(af0, b0, s, 0, 0, 0);
            s = __builtin_amdgcn_mfma_f32_16x16x32_bf16(af1, b1, s, 0, 0, 0);
            #pragma unroll
            for (int reg = 0; reg < 4; ++reg) {
                int row = fg * 4 + reg;            // q-local within sub-tile
                int col = n * 16 + fr;             // k-local (0..63)
                float p = 0.f;
                if (!diag || col <= (sub * 16 + row)) p = __expf(s[reg] * (1.f / 64.f));
                rsum[reg] += p;
                int chunk = col >> 3;
                int off = row * 128 + (((chunk ^ (row & 7)) << 4) | ((col & 7) << 1));
                *reinterpret_cast<u16*>((char*)pw + off) = f2b(p);
            }
        }
        bf16x8 pa0, pa1;
        {
            int c0 = 0 * 4 + fg, c1 = 1 * 4 + fg;
            pa0 = *reinterpret_cast<const bf16x8*>((char*)pw + fr * 128 + ((c0 ^ (fr & 7)) << 4));
            pa1 = *reinterpret_cast<const bf16x8*>((char*)pw + fr * 128 + ((c1 ^ (fr & 7)) << 4));
        }
        #pragma unroll
        for (int n = 0; n < 4; ++n) {
            const u16* vb = vbh + (size_t)(n * 16 + fr) * TT + kt * 64;
            bf16x8 v0 = *reinterpret_cast<const bf16x8*>(vb + fg * 8);
            bf16x8 v1 = *reinterpret_cast<const bf16x8*>(vb + 32 + fg * 8);
            oacc[n] = __builtin_amdgcn_mfma_f32_16x16x32_bf16(pa0, v0, oacc[n], 0, 0, 0);
            oacc[n] = __builtin_amdgcn_mfma_f32_16x16x32_bf16(pa1, v1, oacc[n], 0, 0, 0);
        }
    }
    // combine halves: half-0 publishes partials, half-1 finishes
    if (half == 0) {
        #pragma unroll
        for (int n = 0; n < 4; ++n) comb[sub][lam][n] = oacc[n];
        f32x4 r4 = {rsum[0], rsum[1], rsum[2], rsum[3]};
        comb[sub][lam][4] = r4;
    }
    __syncthreads();
    if (half == 1) {
        #pragma unroll
        for (int n = 0; n < 4; ++n) oacc[n] += comb[sub][lam][n];
        f32x4 r4 = comb[sub][lam][4];
        rsum[0] += r4[0]; rsum[1] += r4[1]; rsum[2] += r4[2]; rsum[3] += r4[3];
        #pragma unroll
        for (int reg = 0; reg < 4; ++reg) {
            float r = rsum[reg];
            r += __shfl_xor(r, 1); r += __shfl_xor(r, 2);
            r += __shfl_xor(r, 4); r += __shfl_xor(r, 8);
            rsum[reg] = 1.f / r;
        }
        int tbase = b * TT + qt * 64 + sub * 16 + fg * 4;
        #pragma unroll
        for (int n = 0; n < 4; ++n) {
            int dcol = hh * 64 + n * 16 + fr;
            #pragma unroll
            for (int reg = 0; reg < 4; ++reg)
                ob[(size_t)(tbase + reg) * NN + dcol] = f2b(oacc[n][reg] * rsum[reg]);
        }
    }
}

extern "C" void kernel_launch(void* const* d_in, const int* in_sizes, int n_in,
                              void* d_out, int out_size, void* d_ws, size_t ws_size,
                              hipStream_t stream) {
    (void)in_sizes; (void)n_in; (void)out_size;
    const int*   tok  = (const int*)d_in[0];
    const float* emb  = (const float*)d_in[1];
    const float* pos  = (const float*)d_in[2];
    const float* ln1s = (const float*)d_in[3];
    const float* ln1b = (const float*)d_in[4];
    const float* qkW  = (const float*)d_in[5];
    const float* vW   = (const float*)d_in[6];
    const float* oW   = (const float*)d_in[7];
    const float* qns  = (const float*)d_in[8];
    const float* qnb  = (const float*)d_in[9];
    const float* kns  = (const float*)d_in[10];
    const float* knb  = (const float*)d_in[11];
    const float* ln2s = (const float*)d_in[12];
    const float* ln2b = (const float*)d_in[13];
    const float* W1   = (const float*)d_in[14];
    const float* W2   = (const float*)d_in[15];
    const float* lnfs = (const float*)d_in[16];
    const float* lnfb = (const float*)d_in[17];
    const float* outW = (const float*)d_in[18];
    const float* outb = (const float*)d_in[19];
    float* out = (float*)d_out;

    const float inv32 = 0.03125f;       // 1/sqrt(N)
    const float betaD = 1.f / 12.f;     // BETA / D
    const size_t LSTRIDE = (size_t)6144 * 1024;       // per-layer Wt elements
    const int NPADV = (VV + 127) & ~127;              // 50304

    // ws: bar 4KB | x f32 4MB | h 2MB | mid 2MB | qh 2MB | kh 2MB | vt 2MB | ob 2MB
    char* p = (char*)d_ws;
    unsigned* bar = (unsigned*)p;  p += 4096;
    float* x   = (float*)p;   p += (size_t)4 << 20;
    u16*   h   = (u16*)p;     p += (size_t)2 << 20;
    u16*   mid = (u16*)p;     p += (size_t)2 << 20;
    u16*   qh  = (u16*)p;     p += (size_t)2 << 20;
    u16*   kh  = (u16*)p;     p += (size_t)2 << 20;
    u16*   vt  = (u16*)p;     p += (size_t)2 << 20;
    u16*   ob  = (u16*)p;     p += (size_t)2 << 20;

    // big path: WtAll 144MB (12 layers) + WtL 50304x1024 bf16 (~98.3MB)
    bool big = ws_size >= ((size_t)265 << 20);
    u16* WtAll = (u16*)p;
    u16* WtL;
    if (big) {
        WtL = WtAll + (size_t)12 * LSTRIDE;
    } else {
        WtL = WtAll + LSTRIDE;            // 32MB chunk buffer (16384 cols)
    }

    hipMemsetAsync(bar, 0, 64, stream);
    embed_k<<<1024, 256, 0, stream>>>(tok, emb, pos, x);
    if (big) {
        transpose5_k<<<dim3(32, 16, 60), 256, 0, stream>>>(qkW, vW, oW, W1, W2,
                WtAll, 0, LSTRIDE);
        transpose_k<<<dim3(NPADV / 64, 16), 256, 0, stream>>>(outW, WtL, VV, VV, NN);
    }

    for (int l = 0; l < NL; ++l) {
        const u16* WtB = big ? WtAll + (size_t)l * LSTRIDE : WtAll;
        if (!big) {
            transpose5_k<<<dim3(32, 16, 5), 256, 0, stream>>>(qkW, vW, oW, W1, W2,
                    WtAll, l, 0);
        }
        // [ln1 -> gridbar -> QKV proj + head-LN + V^T] (768 blocks, 3/CU co-resident)
        gemm_k<32,128,5,0,1><<<dim3(24, 32), 256, 0, stream>>>(h, WtB, vt, qh, kh,
                nullptr, qns + l * HD, qnb + l * HD, kns + l * HD, knb + l * HD,
                NN, 0, 0, 0, inv32, 0.f,
                x, ln1s + l * NN, ln1b + l * NN, h, bar);
        // Fused attention (k-split, 512 threads)
        attn_k<<<dim3(8, 32), 512, 0, stream>>>(qh, kh, vt, ob);
        // Output projection + residual (512 blocks, 2/CU)
        gemm_k<32,64,1><<<dim3(16, 32), 256, 0, stream>>>(ob, WtB + (size_t)3072 * 1024,
                x, nullptr, nullptr, nullptr, nullptr, nullptr, nullptr, nullptr,
                NN, NN, 0, 0, inv32, betaD,
                nullptr, nullptr, nullptr, nullptr, nullptr);
        // [ln2 -> gridbar -> MLP1 + gelu] (512 blocks, 2/CU co-resident)
        gemm_k<32,64,2,0,1><<<dim3(16, 32), 256, 0, stream>>>(h, WtB + (size_t)4096 * 1024,
                mid, nullptr, nullptr, nullptr, nullptr, nullptr, nullptr, nullptr,
                NN, NN, 0, 0, inv32, 0.f,
                x, ln2s + l * NN, ln2b + l * NN, h, bar);
        // MLP2 + residual
        gemm_k<32,64,1><<<dim3(16, 32), 256, 0, stream>>>(mid, WtB + (size_t)5120 * 1024,
                x, nullptr, nullptr, nullptr, nullptr, nullptr, nullptr, nullptr,
                NN, NN, 0, 0, inv32, betaD,
                nullptr, nullptr, nullptr, nullptr, nullptr);
    }
    ln_k<0><<<1024, 256, 0, stream>>>(x, h, lnfs, lnfb);

    if (big) {
        // one logits GEMM, xcd-grouped 1D grid
        gemm_k<128,128,3,1><<<dim3(NPADV / 128 * 8), 256, 0, stream>>>(h, WtL, out,
                nullptr, nullptr, outb, nullptr, nullptr, nullptr, nullptr,
                NN, VV, 0, VV, inv32, 0.f,
                nullptr, nullptr, nullptr, nullptr, nullptr);
    } else {
        for (int c0 = 0; c0 < VV; c0 += 16384) {
            int cn = VV - c0; if (cn > 16384) cn = 16384;
            int npad = (cn + 127) & ~127;
            transpose_k<<<dim3(npad / 64, 16), 256, 0, stream>>>(outW + c0, WtL, cn, VV, NN);
            gemm_k<128,128,3,1><<<dim3(npad / 128 * 8), 256, 0, stream>>>(h, WtL, out,
                    nullptr, nullptr, outb, nullptr, nullptr, nullptr, nullptr,
                    NN, VV, c0, VV, inv32, 0.f,
                    nullptr, nullptr, nullptr, nullptr, nullptr);
        }
    }
}

// Round 15
// 1507.788 us; speedup vs baseline: 1.8409x; 1.8409x over previous
//
#include <hip/hip_runtime.h>
#include <hip/hip_bf16.h>

// Model constants
#define TT 512
#define NN 1024
#define NH 16
#define HD 64
#define NL 12
#define VV 50257

typedef unsigned short u16;
typedef short bf16x8 __attribute__((ext_vector_type(8)));
typedef float f32x4 __attribute__((ext_vector_type(4)));

__device__ __forceinline__ float gelu_f(float x) {
    float x3 = x * x * x;
    return 0.5f * x * (1.0f + tanhf(0.7978845608028654f * (x + 0.044715f * x3)));
}

// fp32 -> bf16 RNE (finite inputs only)
__device__ __forceinline__ u16 f2b(float f) {
    unsigned int u = __float_as_uint(f);
    return (u16)((u + 0x7FFFu + ((u >> 16) & 1u)) >> 16);
}

// async global->LDS, 16B per lane; LDS dest is wave-uniform base + lane*16
__device__ __forceinline__ void gload16(const void* g, void* l) {
    __builtin_amdgcn_global_load_lds(
        (const __attribute__((address_space(1))) unsigned int*)g,
        (__attribute__((address_space(3))) unsigned int*)l,
        16, 0, 0);
}

// x[row,:] = 1024*emb[tok[row],:] + 32*pos[t,:]
__global__ __launch_bounds__(256) void embed_k(const int* __restrict__ tok,
        const float* __restrict__ emb, const float* __restrict__ pos,
        float* __restrict__ x) {
    int row = blockIdx.x;
    int t = row & (TT - 1);
    int tk = tok[row];
    int c = threadIdx.x * 4;
    float4 e = *reinterpret_cast<const float4*>(emb + (size_t)tk * NN + c);
    float4 p = *reinterpret_cast<const float4*>(pos + (size_t)t * NN + c);
    float4 o;
    o.x = 1024.f * e.x + 32.f * p.x;
    o.y = 1024.f * e.y + 32.f * p.y;
    o.z = 1024.f * e.z + 32.f * p.z;
    o.w = 1024.f * e.w + 32.f * p.w;
    *reinterpret_cast<float4*>(x + (size_t)row * NN + c) = o;
}

// Row LayerNorm over N=1024 (+ optional gelu), bf16 output
template<int ACT>
__global__ __launch_bounds__(256) void ln_k(const float* __restrict__ in,
        u16* __restrict__ out, const float* __restrict__ sc, const float* __restrict__ bi) {
    int row = blockIdx.x;
    const float* r = in + (size_t)row * NN;
    int tid = threadIdx.x;
    float v[4]; float s1 = 0.f, s2 = 0.f;
    #pragma unroll
    for (int i = 0; i < 4; ++i) { v[i] = r[tid + i * 256]; s1 += v[i]; s2 += v[i] * v[i]; }
    #pragma unroll
    for (int off = 32; off > 0; off >>= 1) { s1 += __shfl_xor(s1, off); s2 += __shfl_xor(s2, off); }
    __shared__ float red[8];
    __shared__ float st[2];
    int wid = tid >> 6;
    if ((tid & 63) == 0) { red[wid] = s1; red[4 + wid] = s2; }
    __syncthreads();
    if (tid == 0) {
        float a = red[0] + red[1] + red[2] + red[3];
        float b = red[4] + red[5] + red[6] + red[7];
        float mu = a * (1.f / NN);
        float var = b * (1.f / NN) - mu * mu;
        st[0] = mu; st[1] = rsqrtf(var + 1e-6f);
    }
    __syncthreads();
    float mu = st[0], rs = st[1];
    u16* o = out + (size_t)row * NN;
    #pragma unroll
    for (int i = 0; i < 4; ++i) {
        int c = tid + i * 256;
        float y = (v[i] - mu) * rs * sc[c] + bi[c];
        if (ACT) y = gelu_f(y);
        o[c] = f2b(y);
    }
}

// Per-layer weight transpose: z (+5*l0) selects (layer, which of 5 matrices).
// fp32 [1024][Ncols] -> bf16 [Ncols][1024] at Wt + l*lstride + doff.
__global__ __launch_bounds__(256) void transpose5_k(const float* __restrict__ qkW,
        const float* __restrict__ vW, const float* __restrict__ oW,
        const float* __restrict__ W1, const float* __restrict__ W2,
        u16* __restrict__ Wt, int l0, size_t lstride) {
    int z = blockIdx.z + l0 * 5;
    int l = z / 5, which = z - l * 5;
    const float* W; int Ncols; size_t doff;
    switch (which) {
      case 0:  W = qkW + (size_t)l * NN * 2048; Ncols = 2048; doff = 0; break;
      case 1:  W = vW + (size_t)l * NN * NN;  Ncols = 1024; doff = (size_t)2048 * 1024; break;
      case 2:  W = oW + (size_t)l * NN * NN;  Ncols = 1024; doff = (size_t)3072 * 1024; break;
      case 3:  W = W1 + (size_t)l * NN * NN;  Ncols = 1024; doff = (size_t)4096 * 1024; break;
      default: W = W2 + (size_t)l * NN * NN;  Ncols = 1024; doff = (size_t)5120 * 1024; break;
    }
    int n0 = blockIdx.x * 64;
    if (n0 >= Ncols) return;
    int k0 = blockIdx.y * 64;
    u16* dst = Wt + (size_t)l * lstride + doff;
    __shared__ float t[64][65];
    int tid = threadIdx.x;
    #pragma unroll
    for (int j = 0; j < 4; ++j) {
        int e = tid + j * 256;
        int kr = e >> 4, nc = (e & 15) * 4;
        float4 v = *reinterpret_cast<const float4*>(W + (size_t)(k0 + kr) * Ncols + n0 + nc);
        t[kr][nc + 0] = v.x; t[kr][nc + 1] = v.y; t[kr][nc + 2] = v.z; t[kr][nc + 3] = v.w;
    }
    __syncthreads();
    #pragma unroll
    for (int j = 0; j < 4; ++j) {
        int e = tid + j * 256;
        int nr = e >> 4, kc = (e & 15) * 4;
        ushort4 o;
        o.x = f2b(t[kc + 0][nr]);
        o.y = f2b(t[kc + 1][nr]);
        o.z = f2b(t[kc + 2][nr]);
        o.w = f2b(t[kc + 3][nr]);
        *reinterpret_cast<ushort4*>(dst + (size_t)(n0 + nr) * 1024 + k0 + kc) = o;
    }
}

// Guarded single transpose (outW): fp32 [K][Ncols] ld=ldW -> bf16 [Npad][K]
__global__ __launch_bounds__(256) void transpose_k(const float* __restrict__ W,
        u16* __restrict__ Wt, int Ncols, int ldW, int K) {
    __shared__ float t[64][65];
    int n0 = blockIdx.x * 64, k0 = blockIdx.y * 64;
    int tid = threadIdx.x;
    #pragma unroll
    for (int j = 0; j < 4; ++j) {
        int e = tid + j * 256;
        int kr = e >> 4, nc = (e & 15) * 4;
        int n = n0 + nc;
        float4 v = {0.f, 0.f, 0.f, 0.f};
        if (n + 3 < Ncols) {
            v = *reinterpret_cast<const float4*>(W + (size_t)(k0 + kr) * ldW + n);
        } else {
            if (n + 0 < Ncols) v.x = W[(size_t)(k0 + kr) * ldW + n + 0];
            if (n + 1 < Ncols) v.y = W[(size_t)(k0 + kr) * ldW + n + 1];
            if (n + 2 < Ncols) v.z = W[(size_t)(k0 + kr) * ldW + n + 2];
        }
        t[kr][nc + 0] = v.x; t[kr][nc + 1] = v.y; t[kr][nc + 2] = v.z; t[kr][nc + 3] = v.w;
    }
    __syncthreads();
    #pragma unroll
    for (int j = 0; j < 4; ++j) {
        int e = tid + j * 256;
        int nr = e >> 4, kc = (e & 15) * 4;
        ushort4 o;
        o.x = f2b(t[kc + 0][nr]);
        o.y = f2b(t[kc + 1][nr]);
        o.z = f2b(t[kc + 2][nr]);
        o.w = f2b(t[kc + 3][nr]);
        *reinterpret_cast<ushort4*>(Wt + (size_t)(n0 + nr) * K + k0 + kc) = o;
    }
}

// swizzled LDS fragment read: row r, logical 16B chunk c
__device__ __forceinline__ bf16x8 ldsfrag(const u16* base, int r, int c) {
    int off = r * 64 + ((c ^ (r & 7)) << 3);
    return *reinterpret_cast<const bf16x8*>(base + off);
}

// MFMA GEMM, TMxTN tile, BK=64, SINGLE-buffer LDS (m97 structure).
// XCDMAP=1: 1D grid (8*k); all 8 m-tiles of a B-panel on the SAME XCD.
// EPI 1: fp32 C += rbeta*(acc*scale)
// EPI 2: bf16 C = gelu(acc*scale)
// EPI 3: fp32 C[row*ldC+coff+n] = (acc+bias)*scale — LDS-transposed, float4
//        coalesced stores (256B/16-lane group), guarded coff+n<cmax
// EPI 5: fused QKV: n0<2048 -> per-head LN -> qh(C2)/kh(C3); else V^T -> vt(C)
template<int TM, int TN, int EPI, int XCDMAP = 0>
__global__ __launch_bounds__(256) void gemm_k(const u16* __restrict__ A,
        const u16* __restrict__ Bt, void* __restrict__ C,
        void* __restrict__ C2, void* __restrict__ C3,
        const float* __restrict__ bias,
        const float* __restrict__ qs, const float* __restrict__ qb,
        const float* __restrict__ ks, const float* __restrict__ kb,
        int K, int ldC, int coff, int cmax, float scale, float rbeta) {
    constexpr int MF = TM / 32, NF = TN / 32;     // frags per wave
    constexpr int IA = TM / 8, IB = TN / 8;       // 1KB staging issues
    __shared__ __align__(16) u16 As[TM * 64];
    __shared__ __align__(16) u16 Bs[TN * 64];
    int tid = threadIdx.x;
    int lam = tid & 63, w = tid >> 6;
    int m0, n0;
    if (XCDMAP) {
        int i = blockIdx.x;
        int per = gridDim.x >> 3;          // jobs per XCD
        int j = (i & 7) * per + (i >> 3);  // xcd-grouped job id
        m0 = (j & 7) * TM;                 // 8 m-tiles cycle fastest
        n0 = (j >> 3) * TN;                // consecutive panels per XCD
    } else {
        m0 = blockIdx.y * TM;
        n0 = blockIdx.x * TN;
    }
    int lr = lam >> 3;              // row-in-8 within a 1KB issue
    int lc = (lam & 7) ^ lr;        // inverse-swizzled logical chunk
    const u16* Abase = A + (size_t)m0 * K;
    const u16* Bbase = Bt + (size_t)n0 * K;
    int wr = (w >> 1) * (TM / 2), wc = (w & 1) * (TN / 2);
    int fr = lam & 15, fg = lam >> 4;
    f32x4 acc[MF][NF];
    #pragma unroll
    for (int i = 0; i < MF; ++i)
        #pragma unroll
        for (int j = 0; j < NF; ++j) acc[i][j] = (f32x4)0.0f;

    for (int k0 = 0; k0 < K; k0 += 64) {
        #pragma unroll
        for (int i = 0; i < IA / 4; ++i) {
            int q = w * (IA / 4) + i;
            int r = q * 8 + lr;
            gload16(Abase + (size_t)r * K + k0 + lc * 8, (char*)As + q * 1024);
        }
        #pragma unroll
        for (int i = 0; i < IB / 4; ++i) {
            int q = w * (IB / 4) + i;
            int r = q * 8 + lr;
            gload16(Bbase + (size_t)r * K + k0 + lc * 8, (char*)Bs + q * 1024);
        }
        __syncthreads();                   // drains vmcnt(0) + barrier
        #pragma unroll
        for (int s = 0; s < 2; ++s) {
            bf16x8 af[MF], bfv[NF];
            #pragma unroll
            for (int m = 0; m < MF; ++m) af[m] = ldsfrag(As, wr + m * 16 + fr, s * 4 + fg);
            #pragma unroll
            for (int n = 0; n < NF; ++n) bfv[n] = ldsfrag(Bs, wc + n * 16 + fr, s * 4 + fg);
            #pragma unroll
            for (int m = 0; m < MF; ++m)
                #pragma unroll
                for (int n = 0; n < NF; ++n)
                    acc[m][n] = __builtin_amdgcn_mfma_f32_16x16x32_bf16(af[m], bfv[n], acc[m][n], 0, 0, 0);
        }
        if (k0 + 64 < K) __syncthreads();  // protect LDS overwrite
    }

    // C/D layout: col = lane&15, row = (lane>>4)*4 + reg
    if constexpr (EPI == 3) {
        // LDS-transposed coalesced store: per-wave 16x64 fp32 tile, row-contig read-back
        __shared__ __align__(16) float ct[4][16][68];   // stride 68 -> 16B-aligned rows
        #pragma unroll
        for (int m = 0; m < MF; ++m) {
            #pragma unroll
            for (int n = 0; n < NF; ++n)
                #pragma unroll
                for (int reg = 0; reg < 4; ++reg)
                    ct[w][fg * 4 + reg][n * 16 + fr] = acc[m][n][reg];
            asm volatile("s_waitcnt lgkmcnt(0)" ::: "memory");  // wave DS drain before x-lane read
            #pragma unroll
            for (int s2 = 0; s2 < 4; ++s2) {
                int r = (lam >> 4) + s2 * 4;
                int c0 = (lam & 15) * 4;
                float4 v = *reinterpret_cast<float4*>(&ct[w][r][c0]);
                int row = m0 + wr + m * 16 + r;
                int gc = coff + n0 + wc + c0;
                float* dst = (float*)C + (size_t)row * ldC + gc;
                if (gc + 3 < cmax) {
                    float4 b4 = *reinterpret_cast<const float4*>(bias + gc);
                    float4 o4;
                    o4.x = (v.x + b4.x) * scale;
                    o4.y = (v.y + b4.y) * scale;
                    o4.z = (v.z + b4.z) * scale;
                    o4.w = (v.w + b4.w) * scale;
                    *reinterpret_cast<float4*>(dst) = o4;
                } else {
                    float vv[4] = {v.x, v.y, v.z, v.w};
                    #pragma unroll
                    for (int j = 0; j < 4; ++j)
                        if (gc + j < cmax) dst[j] = (vv[j] + bias[gc + j]) * scale;
                }
            }
            asm volatile("s_waitcnt lgkmcnt(0)" ::: "memory");  // reads done before next m overwrite
        }
        return;
    }
    if (EPI == 5) {
        if (n0 < 2048) {
            int sq = wc >> 6;                    // 0 = q half, 1 = k half
            int head = n0 >> 7;
            const float* scp = sq ? ks : qs;
            const float* bip = sq ? kb : qb;
            u16* dst = (u16*)(sq ? C3 : C2);
            float scv[NF], biv[NF];
            #pragma unroll
            for (int n = 0; n < NF; ++n) { scv[n] = scp[n * 16 + fr]; biv[n] = bip[n * 16 + fr]; }
            #pragma unroll
            for (int m = 0; m < MF; ++m) {
                #pragma unroll
                for (int reg = 0; reg < 4; ++reg) {
                    float v[NF]; float s1 = 0.f, s2 = 0.f;
                    #pragma unroll
                    for (int n = 0; n < NF; ++n) {
                        v[n] = acc[m][n][reg] * scale;
                        s1 += v[n]; s2 += v[n] * v[n];
                    }
                    #pragma unroll
                    for (int off = 1; off < 16; off <<= 1) {
                        s1 += __shfl_xor(s1, off);
                        s2 += __shfl_xor(s2, off);
                    }
                    float mu = s1 * (1.f / 64.f);
                    float var = s2 * (1.f / 64.f) - mu * mu;
                    float rs = rsqrtf(var + 1e-6f);
                    int row = m0 + wr + m * 16 + 4 * fg + reg;
                    int bb = row >> 9, t = row & (TT - 1);
                    size_t base = ((size_t)(bb * NH + head) * TT + t) * HD;
                    #pragma unroll
                    for (int n = 0; n < NF; ++n)
                        dst[base + n * 16 + fr] = f2b((v[n] - mu) * rs * scv[n] + biv[n]);
                }
            }
        } else {
            #pragma unroll
            for (int m = 0; m < MF; ++m) {
                int row0 = m0 + wr + m * 16 + 4 * fg;
                int bb = row0 >> 9, t0 = row0 & (TT - 1);
                #pragma unroll
                for (int n = 0; n < NF; ++n) {
                    int colv = n0 - 2048 + wc + n * 16 + fr;
                    int hh = colv >> 6, dd = colv & 63;
                    ushort4 o4;
                    o4.x = f2b(acc[m][n][0] * scale);
                    o4.y = f2b(acc[m][n][1] * scale);
                    o4.z = f2b(acc[m][n][2] * scale);
                    o4.w = f2b(acc[m][n][3] * scale);
                    *reinterpret_cast<ushort4*>((u16*)C +
                        (((size_t)(bb * NH + hh) * HD + dd) * TT + t0)) = o4;
                }
            }
        }
        return;
    }
    #pragma unroll
    for (int m = 0; m < MF; ++m) {
        #pragma unroll
        for (int n = 0; n < NF; ++n) {
            int ncol = n0 + wc + n * 16 + fr;
            int mrow = m0 + wr + m * 16 + 4 * fg;
            #pragma unroll
            for (int reg = 0; reg < 4; ++reg) {
                int row = mrow + reg;
                float v = acc[m][n][reg];
                if (EPI == 1) {
                    float* p = (float*)C + (size_t)row * ldC + ncol;
                    *p = *p + rbeta * (v * scale);
                } else if (EPI == 2) {
                    ((u16*)C)[(size_t)row * ldC + ncol] = f2b(gelu_f(v * scale));
                }
            }
        }
    }
}

// Fused flash attention, k-split: per (qt, bh) block, 8 waves (512 thr).
// Wave (sub, half): sub = q-subtile (16 rows), half = kt parity. Both halves
// accumulate unnormalized partial sums (no max-sub => split-K is exact);
// combine via LDS, then normalize.
__global__ __launch_bounds__(512) void attn_k(const u16* __restrict__ qh,
        const u16* __restrict__ kh, const u16* __restrict__ vt,
        u16* __restrict__ ob) {
    int qt = blockIdx.x, bh = blockIdx.y;
    int b = bh >> 4, hh = bh & 15;
    int tid = threadIdx.x;
    int w = tid >> 6, lam = tid & 63;
    int sub = w & 3, half = w >> 2;
    int fr = lam & 15, fg = lam >> 4;
    __shared__ __align__(16) u16 ps[8][16 * 64];   // per-wave P tile, XOR-swizzled
    __shared__ __align__(16) f32x4 comb[4][64][5]; // half-0 partials: oacc[4] + rsum
    u16* pw = ps[w];
    const u16* qbase = qh + ((size_t)bh * TT + qt * 64 + sub * 16) * HD;
    bf16x8 af0 = *reinterpret_cast<const bf16x8*>(qbase + (size_t)fr * HD + fg * 8);
    bf16x8 af1 = *reinterpret_cast<const bf16x8*>(qbase + (size_t)fr * HD + 32 + fg * 8);
    f32x4 oacc[4];
    #pragma unroll
    for (int n = 0; n < 4; ++n) oacc[n] = (f32x4)0.0f;
    float rsum[4] = {0.f, 0.f, 0.f, 0.f};
    const u16* vbh = vt + (size_t)bh * HD * TT;
    for (int kt = half; kt <= qt; kt += 2) {
        const u16* kbase = kh + ((size_t)bh * TT + kt * 64) * HD;
        bool diag = (kt == qt);
        #pragma unroll
        for (int n = 0; n < 4; ++n) {
            bf16x8 b0 = *reinterpret_cast<const bf16x8*>(kbase + (size_t)(n * 16 + fr) * HD + fg * 8);
            bf16x8 b1 = *reinterpret_cast<const bf16x8*>(kbase + (size_t)(n * 16 + fr) * HD + 32 + fg * 8);
            f32x4 s = (f32x4)0.0f;
            s = __builtin_amdgcn_mfma_f32_16x16x32_bf16(af0, b0, s, 0, 0, 0);
            s = __builtin_amdgcn_mfma_f32_16x16x32_bf16(af1, b1, s, 0, 0, 0);
            #pragma unroll
            for (int reg = 0; reg < 4; ++reg) {
                int row = fg * 4 + reg;            // q-local within sub-tile
                int col = n * 16 + fr;             // k-local (0..63)
                float p = 0.f;
                if (!diag || col <= (sub * 16 + row)) p = __expf(s[reg] * (1.f / 64.f));
                rsum[reg] += p;
                int chunk = col >> 3;
                int off = row * 128 + (((chunk ^ (row & 7)) << 4) | ((col & 7) << 1));
                *reinterpret_cast<u16*>((char*)pw + off) = f2b(p);
            }
        }
        bf16x8 pa0, pa1;
        {
            int c0 = 0 * 4 + fg, c1 = 1 * 4 + fg;
            pa0 = *reinterpret_cast<const bf16x8*>((char*)pw + fr * 128 + ((c0 ^ (fr & 7)) << 4));
            pa1 = *reinterpret_cast<const bf16x8*>((char*)pw + fr * 128 + ((c1 ^ (fr & 7)) << 4));
        }
        #pragma unroll
        for (int n = 0; n < 4; ++n) {
            const u16* vb = vbh + (size_t)(n * 16 + fr) * TT + kt * 64;
            bf16x8 v0 = *reinterpret_cast<const bf16x8*>(vb + fg * 8);
            bf16x8 v1 = *reinterpret_cast<const bf16x8*>(vb + 32 + fg * 8);
            oacc[n] = __builtin_amdgcn_mfma_f32_16x16x32_bf16(pa0, v0, oacc[n], 0, 0, 0);
            oacc[n] = __builtin_amdgcn_mfma_f32_16x16x32_bf16(pa1, v1, oacc[n], 0, 0, 0);
        }
    }
    // combine halves: half-0 publishes partials, half-1 finishes
    if (half == 0) {
        #pragma unroll
        for (int n = 0; n < 4; ++n) comb[sub][lam][n] = oacc[n];
        f32x4 r4 = {rsum[0], rsum[1], rsum[2], rsum[3]};
        comb[sub][lam][4] = r4;
    }
    __syncthreads();
    if (half == 1) {
        #pragma unroll
        for (int n = 0; n < 4; ++n) oacc[n] += comb[sub][lam][n];
        f32x4 r4 = comb[sub][lam][4];
        rsum[0] += r4[0]; rsum[1] += r4[1]; rsum[2] += r4[2]; rsum[3] += r4[3];
        #pragma unroll
        for (int reg = 0; reg < 4; ++reg) {
            float r = rsum[reg];
            r += __shfl_xor(r, 1); r += __shfl_xor(r, 2);
            r += __shfl_xor(r, 4); r += __shfl_xor(r, 8);
            rsum[reg] = 1.f / r;
        }
        int tbase = b * TT + qt * 64 + sub * 16 + fg * 4;
        #pragma unroll
        for (int n = 0; n < 4; ++n) {
            int dcol = hh * 64 + n * 16 + fr;
            #pragma unroll
            for (int reg = 0; reg < 4; ++reg)
                ob[(size_t)(tbase + reg) * NN + dcol] = f2b(oacc[n][reg] * rsum[reg]);
        }
    }
}

extern "C" void kernel_launch(void* const* d_in, const int* in_sizes, int n_in,
                              void* d_out, int out_size, void* d_ws, size_t ws_size,
                              hipStream_t stream) {
    (void)in_sizes; (void)n_in; (void)out_size;
    const int*   tok  = (const int*)d_in[0];
    const float* emb  = (const float*)d_in[1];
    const float* pos  = (const float*)d_in[2];
    const float* ln1s = (const float*)d_in[3];
    const float* ln1b = (const float*)d_in[4];
    const float* qkW  = (const float*)d_in[5];
    const float* vW   = (const float*)d_in[6];
    const float* oW   = (const float*)d_in[7];
    const float* qns  = (const float*)d_in[8];
    const float* qnb  = (const float*)d_in[9];
    const float* kns  = (const float*)d_in[10];
    const float* knb  = (const float*)d_in[11];
    const float* ln2s = (const float*)d_in[12];
    const float* ln2b = (const float*)d_in[13];
    const float* W1   = (const float*)d_in[14];
    const float* W2   = (const float*)d_in[15];
    const float* lnfs = (const float*)d_in[16];
    const float* lnfb = (const float*)d_in[17];
    const float* outW = (const float*)d_in[18];
    const float* outb = (const float*)d_in[19];
    float* out = (float*)d_out;

    const float inv32 = 0.03125f;       // 1/sqrt(N)
    const float betaD = 1.f / 12.f;     // BETA / D
    const size_t LSTRIDE = (size_t)6144 * 1024;       // per-layer Wt elements
    const int NPADV = (VV + 127) & ~127;              // 50304

    // Acts: x f32 4MB | h 2MB | mid 2MB | qh 2MB | kh 2MB | vt 2MB | ob 2MB = 16MB
    char* p = (char*)d_ws;
    float* x   = (float*)p;   p += (size_t)4 << 20;
    u16*   h   = (u16*)p;     p += (size_t)2 << 20;
    u16*   mid = (u16*)p;     p += (size_t)2 << 20;
    u16*   qh  = (u16*)p;     p += (size_t)2 << 20;
    u16*   kh  = (u16*)p;     p += (size_t)2 << 20;
    u16*   vt  = (u16*)p;     p += (size_t)2 << 20;
    u16*   ob  = (u16*)p;     p += (size_t)2 << 20;

    // big path: WtAll 144MB (12 layers) + WtL 50304x1024 bf16 (~98.3MB) => 264MB total
    bool big = ws_size >= ((size_t)264 << 20);
    u16* WtAll = (u16*)p;     // big: 144MB; small: 12MB single-layer buffer
    u16* WtL;
    if (big) {
        WtL = WtAll + (size_t)12 * LSTRIDE;
    } else {
        WtL = WtAll + LSTRIDE;            // 32MB chunk buffer (16384 cols)
    }

    embed_k<<<1024, 256, 0, stream>>>(tok, emb, pos, x);
    if (big) {
        // all 60 weight transposes in one launch
        transpose5_k<<<dim3(32, 16, 60), 256, 0, stream>>>(qkW, vW, oW, W1, W2,
                WtAll, 0, LSTRIDE);
        // full outW transpose (padded rows zero-filled)
        transpose_k<<<dim3(NPADV / 64, 16), 256, 0, stream>>>(outW, WtL, VV, VV, NN);
    }

    for (int l = 0; l < NL; ++l) {
        const u16* WtB = big ? WtAll + (size_t)l * LSTRIDE : WtAll;
        ln_k<1><<<1024, 256, 0, stream>>>(x, h, ln1s + l * NN, ln1b + l * NN);
        if (!big) {
            transpose5_k<<<dim3(32, 16, 5), 256, 0, stream>>>(qkW, vW, oW, W1, W2,
                    WtAll, l, 0);
        }
        // Fused QKV projection + per-head LN + V^T store (768 blocks, 3/CU)
        gemm_k<32,128,5><<<dim3(24, 32), 256, 0, stream>>>(h, WtB, vt, qh, kh,
                nullptr, qns + l * HD, qnb + l * HD, kns + l * HD, knb + l * HD,
                NN, 0, 0, 0, inv32, 0.f);
        // Fused attention (k-split, 512 threads)
        attn_k<<<dim3(8, 32), 512, 0, stream>>>(qh, kh, vt, ob);
        // Output projection + residual (512 blocks, 2/CU)
        gemm_k<32,64,1><<<dim3(16, 32), 256, 0, stream>>>(ob, WtB + (size_t)3072 * 1024,
                x, nullptr, nullptr, nullptr, nullptr, nullptr, nullptr, nullptr,
                NN, NN, 0, 0, inv32, betaD);
        // MLP
        ln_k<1><<<1024, 256, 0, stream>>>(x, h, ln2s + l * NN, ln2b + l * NN);
        gemm_k<32,64,2><<<dim3(16, 32), 256, 0, stream>>>(h, WtB + (size_t)4096 * 1024,
                mid, nullptr, nullptr, nullptr, nullptr, nullptr, nullptr, nullptr,
                NN, NN, 0, 0, inv32, 0.f);
        gemm_k<32,64,1><<<dim3(16, 32), 256, 0, stream>>>(mid, WtB + (size_t)5120 * 1024,
                x, nullptr, nullptr, nullptr, nullptr, nullptr, nullptr, nullptr,
                NN, NN, 0, 0, inv32, betaD);
    }
    ln_k<0><<<1024, 256, 0, stream>>>(x, h, lnfs, lnfb);

    if (big) {
        // one logits GEMM, xcd-grouped 1D grid: all 8 m-tiles of a panel on one XCD
        gemm_k<128,128,3,1><<<dim3(NPADV / 128 * 8), 256, 0, stream>>>(h, WtL, out,
                nullptr, nullptr, outb, nullptr, nullptr, nullptr, nullptr,
                NN, VV, 0, VV, inv32, 0.f);
    } else {
        for (int c0 = 0; c0 < VV; c0 += 16384) {
            int cn = VV - c0; if (cn > 16384) cn = 16384;
            int npad = (cn + 127) & ~127;
            transpose_k<<<dim3(npad / 64, 16), 256, 0, stream>>>(outW + c0, WtL, cn, VV, NN);
            gemm_k<128,128,3,1><<<dim3(npad / 128 * 8), 256, 0, stream>>>(h, WtL, out,
                    nullptr, nullptr, outb, nullptr, nullptr, nullptr, nullptr,
                    NN, VV, c0, VV, inv32, 0.f);
        }
    }
}

// Round 16
// 1443.960 us; speedup vs baseline: 1.9222x; 1.0442x over previous
//
#include <hip/hip_runtime.h>
#include <hip/hip_bf16.h>

// Model constants
#define TT 512
#define NN 1024
#define NH 16
#define HD 64
#define NL 12
#define VV 50257

typedef unsigned short u16;
typedef short bf16x8 __attribute__((ext_vector_type(8)));
typedef float f32x4 __attribute__((ext_vector_type(4)));

__device__ __forceinline__ float gelu_f(float x) {
    float x3 = x * x * x;
    return 0.5f * x * (1.0f + tanhf(0.7978845608028654f * (x + 0.044715f * x3)));
}

// fp32 -> bf16 RNE (finite inputs only)
__device__ __forceinline__ u16 f2b(float f) {
    unsigned int u = __float_as_uint(f);
    return (u16)((u + 0x7FFFu + ((u >> 16) & 1u)) >> 16);
}

// async global->LDS, 16B per lane; LDS dest is wave-uniform base + lane*16
__device__ __forceinline__ void gload16(const void* g, void* l) {
    __builtin_amdgcn_global_load_lds(
        (const __attribute__((address_space(1))) unsigned int*)g,
        (__attribute__((address_space(3))) unsigned int*)l,
        16, 0, 0);
}

// x[row,:] = 1024*emb[tok[row],:] + 32*pos[t,:]
__global__ __launch_bounds__(256) void embed_k(const int* __restrict__ tok,
        const float* __restrict__ emb, const float* __restrict__ pos,
        float* __restrict__ x) {
    int row = blockIdx.x;
    int t = row & (TT - 1);
    int tk = tok[row];
    int c = threadIdx.x * 4;
    float4 e = *reinterpret_cast<const float4*>(emb + (size_t)tk * NN + c);
    float4 p = *reinterpret_cast<const float4*>(pos + (size_t)t * NN + c);
    float4 o;
    o.x = 1024.f * e.x + 32.f * p.x;
    o.y = 1024.f * e.y + 32.f * p.y;
    o.z = 1024.f * e.z + 32.f * p.z;
    o.w = 1024.f * e.w + 32.f * p.w;
    *reinterpret_cast<float4*>(x + (size_t)row * NN + c) = o;
}

// Row LayerNorm over N=1024 (+ optional gelu), bf16 output
template<int ACT>
__global__ __launch_bounds__(256) void ln_k(const float* __restrict__ in,
        u16* __restrict__ out, const float* __restrict__ sc, const float* __restrict__ bi) {
    int row = blockIdx.x;
    const float* r = in + (size_t)row * NN;
    int tid = threadIdx.x;
    float v[4]; float s1 = 0.f, s2 = 0.f;
    #pragma unroll
    for (int i = 0; i < 4; ++i) { v[i] = r[tid + i * 256]; s1 += v[i]; s2 += v[i] * v[i]; }
    #pragma unroll
    for (int off = 32; off > 0; off >>= 1) { s1 += __shfl_xor(s1, off); s2 += __shfl_xor(s2, off); }
    __shared__ float red[8];
    __shared__ float st[2];
    int wid = tid >> 6;
    if ((tid & 63) == 0) { red[wid] = s1; red[4 + wid] = s2; }
    __syncthreads();
    if (tid == 0) {
        float a = red[0] + red[1] + red[2] + red[3];
        float b = red[4] + red[5] + red[6] + red[7];
        float mu = a * (1.f / NN);
        float var = b * (1.f / NN) - mu * mu;
        st[0] = mu; st[1] = rsqrtf(var + 1e-6f);
    }
    __syncthreads();
    float mu = st[0], rs = st[1];
    u16* o = out + (size_t)row * NN;
    #pragma unroll
    for (int i = 0; i < 4; ++i) {
        int c = tid + i * 256;
        float y = (v[i] - mu) * rs * sc[c] + bi[c];
        if (ACT) y = gelu_f(y);
        o[c] = f2b(y);
    }
}

// Per-layer weight transpose: z (+5*l0) selects (layer, which of 5 matrices).
// fp32 [1024][Ncols] -> bf16 [Ncols][1024] at Wt + l*lstride + doff.
__global__ __launch_bounds__(256) void transpose5_k(const float* __restrict__ qkW,
        const float* __restrict__ vW, const float* __restrict__ oW,
        const float* __restrict__ W1, const float* __restrict__ W2,
        u16* __restrict__ Wt, int l0, size_t lstride) {
    int z = blockIdx.z + l0 * 5;
    int l = z / 5, which = z - l * 5;
    const float* W; int Ncols; size_t doff;
    switch (which) {
      case 0:  W = qkW + (size_t)l * NN * 2048; Ncols = 2048; doff = 0; break;
      case 1:  W = vW + (size_t)l * NN * NN;  Ncols = 1024; doff = (size_t)2048 * 1024; break;
      case 2:  W = oW + (size_t)l * NN * NN;  Ncols = 1024; doff = (size_t)3072 * 1024; break;
      case 3:  W = W1 + (size_t)l * NN * NN;  Ncols = 1024; doff = (size_t)4096 * 1024; break;
      default: W = W2 + (size_t)l * NN * NN;  Ncols = 1024; doff = (size_t)5120 * 1024; break;
    }
    int n0 = blockIdx.x * 64;
    if (n0 >= Ncols) return;
    int k0 = blockIdx.y * 64;
    u16* dst = Wt + (size_t)l * lstride + doff;
    __shared__ float t[64][65];
    int tid = threadIdx.x;
    #pragma unroll
    for (int j = 0; j < 4; ++j) {
        int e = tid + j * 256;
        int kr = e >> 4, nc = (e & 15) * 4;
        float4 v = *reinterpret_cast<const float4*>(W + (size_t)(k0 + kr) * Ncols + n0 + nc);
        t[kr][nc + 0] = v.x; t[kr][nc + 1] = v.y; t[kr][nc + 2] = v.z; t[kr][nc + 3] = v.w;
    }
    __syncthreads();
    #pragma unroll
    for (int j = 0; j < 4; ++j) {
        int e = tid + j * 256;
        int nr = e >> 4, kc = (e & 15) * 4;
        ushort4 o;
        o.x = f2b(t[kc + 0][nr]);
        o.y = f2b(t[kc + 1][nr]);
        o.z = f2b(t[kc + 2][nr]);
        o.w = f2b(t[kc + 3][nr]);
        *reinterpret_cast<ushort4*>(dst + (size_t)(n0 + nr) * 1024 + k0 + kc) = o;
    }
}

// Guarded single transpose (outW): fp32 [K][Ncols] ld=ldW -> bf16 [Npad][K]
__global__ __launch_bounds__(256) void transpose_k(const float* __restrict__ W,
        u16* __restrict__ Wt, int Ncols, int ldW, int K) {
    __shared__ float t[64][65];
    int n0 = blockIdx.x * 64, k0 = blockIdx.y * 64;
    int tid = threadIdx.x;
    #pragma unroll
    for (int j = 0; j < 4; ++j) {
        int e = tid + j * 256;
        int kr = e >> 4, nc = (e & 15) * 4;
        int n = n0 + nc;
        float4 v = {0.f, 0.f, 0.f, 0.f};
        if (n + 3 < Ncols) {
            v = *reinterpret_cast<const float4*>(W + (size_t)(k0 + kr) * ldW + n);
        } else {
            if (n + 0 < Ncols) v.x = W[(size_t)(k0 + kr) * ldW + n + 0];
            if (n + 1 < Ncols) v.y = W[(size_t)(k0 + kr) * ldW + n + 1];
            if (n + 2 < Ncols) v.z = W[(size_t)(k0 + kr) * ldW + n + 2];
        }
        t[kr][nc + 0] = v.x; t[kr][nc + 1] = v.y; t[kr][nc + 2] = v.z; t[kr][nc + 3] = v.w;
    }
    __syncthreads();
    #pragma unroll
    for (int j = 0; j < 4; ++j) {
        int e = tid + j * 256;
        int nr = e >> 4, kc = (e & 15) * 4;
        ushort4 o;
        o.x = f2b(t[kc + 0][nr]);
        o.y = f2b(t[kc + 1][nr]);
        o.z = f2b(t[kc + 2][nr]);
        o.w = f2b(t[kc + 3][nr]);
        *reinterpret_cast<ushort4*>(Wt + (size_t)(n0 + nr) * K + k0 + kc) = o;
    }
}

// swizzled LDS fragment read: row r, logical 16B chunk c
__device__ __forceinline__ bf16x8 ldsfrag(const u16* base, int r, int c) {
    int off = r * 64 + ((c ^ (r & 7)) << 3);
    return *reinterpret_cast<const bf16x8*>(base + off);
}

// MFMA GEMM, TMxTN tile, BK=64, SINGLE-buffer LDS (m97 structure).
// XCDMAP=1: 1D grid (8*k); all 8 m-tiles of a B-panel on the SAME XCD.
// EPI 1/2/3 use SWAPPED mfma operand order (acc = mfma(B,A,acc)) so a lane's
// 4 accumulator regs map to 4 CONSECUTIVE C columns -> float4/ushort4 stores
// (m89 layout: col=lane&15 follows operand-B, row=(lane>>4)*4+reg follows A).
// EPI 1: fp32 C += rbeta*(acc*scale)      (float4 RMW)
// EPI 2: bf16 C = gelu(acc*scale)         (ushort4 store)
// EPI 3: fp32 C[row][coff+n] = (acc+bias)*scale  (float4 + bias float4, tail-guarded)
// EPI 5: fused QKV (UNSWAPPED): n0<2048 -> per-head LN -> qh(C2)/kh(C3);
//        else V^T store vt(C) bf16 [bh][d][t]
template<int TM, int TN, int EPI, int XCDMAP = 0>
__global__ __launch_bounds__(256) void gemm_k(const u16* __restrict__ A,
        const u16* __restrict__ Bt, void* __restrict__ C,
        void* __restrict__ C2, void* __restrict__ C3,
        const float* __restrict__ bias,
        const float* __restrict__ qs, const float* __restrict__ qb,
        const float* __restrict__ ks, const float* __restrict__ kb,
        int K, int ldC, int coff, int cmax, float scale, float rbeta) {
    constexpr int MF = TM / 32, NF = TN / 32;     // frags per wave
    constexpr int IA = TM / 8, IB = TN / 8;       // 1KB staging issues
    constexpr bool SW = (EPI != 5);               // swapped operand order
    __shared__ __align__(16) u16 As[TM * 64];
    __shared__ __align__(16) u16 Bs[TN * 64];
    int tid = threadIdx.x;
    int lam = tid & 63, w = tid >> 6;
    int m0, n0;
    if (XCDMAP) {
        int i = blockIdx.x;
        int per = gridDim.x >> 3;          // jobs per XCD
        int j = (i & 7) * per + (i >> 3);  // xcd-grouped job id
        m0 = (j & 7) * TM;                 // 8 m-tiles cycle fastest
        n0 = (j >> 3) * TN;                // consecutive panels per XCD
    } else {
        m0 = blockIdx.y * TM;
        n0 = blockIdx.x * TN;
    }
    int lr = lam >> 3;              // row-in-8 within a 1KB issue
    int lc = (lam & 7) ^ lr;        // inverse-swizzled logical chunk
    const u16* Abase = A + (size_t)m0 * K;
    const u16* Bbase = Bt + (size_t)n0 * K;
    int wr = (w >> 1) * (TM / 2), wc = (w & 1) * (TN / 2);
    int fr = lam & 15, fg = lam >> 4;
    f32x4 acc[MF][NF];
    #pragma unroll
    for (int i = 0; i < MF; ++i)
        #pragma unroll
        for (int j = 0; j < NF; ++j) acc[i][j] = (f32x4)0.0f;

    for (int k0 = 0; k0 < K; k0 += 64) {
        #pragma unroll
        for (int i = 0; i < IA / 4; ++i) {
            int q = w * (IA / 4) + i;
            int r = q * 8 + lr;
            gload16(Abase + (size_t)r * K + k0 + lc * 8, (char*)As + q * 1024);
        }
        #pragma unroll
        for (int i = 0; i < IB / 4; ++i) {
            int q = w * (IB / 4) + i;
            int r = q * 8 + lr;
            gload16(Bbase + (size_t)r * K + k0 + lc * 8, (char*)Bs + q * 1024);
        }
        __syncthreads();                   // drains vmcnt(0) + barrier
        #pragma unroll
        for (int s = 0; s < 2; ++s) {
            bf16x8 af[MF], bfv[NF];
            #pragma unroll
            for (int m = 0; m < MF; ++m) af[m] = ldsfrag(As, wr + m * 16 + fr, s * 4 + fg);
            #pragma unroll
            for (int n = 0; n < NF; ++n) bfv[n] = ldsfrag(Bs, wc + n * 16 + fr, s * 4 + fg);
            #pragma unroll
            for (int m = 0; m < MF; ++m)
                #pragma unroll
                for (int n = 0; n < NF; ++n) {
                    if (SW)
                        acc[m][n] = __builtin_amdgcn_mfma_f32_16x16x32_bf16(bfv[n], af[m], acc[m][n], 0, 0, 0);
                    else
                        acc[m][n] = __builtin_amdgcn_mfma_f32_16x16x32_bf16(af[m], bfv[n], acc[m][n], 0, 0, 0);
                }
        }
        if (k0 + 64 < K) __syncthreads();  // protect LDS overwrite
    }

    if constexpr (SW) {
        // Swapped layout: C row = m0+wr+m*16+fr, C cols = n0+wc+n*16+4*fg+{0..3}
        #pragma unroll
        for (int m = 0; m < MF; ++m) {
            int row = m0 + wr + m * 16 + fr;
            #pragma unroll
            for (int n = 0; n < NF; ++n) {
                int colb = n0 + wc + n * 16 + 4 * fg;
                f32x4 a4 = acc[m][n];
                if (EPI == 1) {
                    float* p = (float*)C + (size_t)row * ldC + colb;
                    float4 x4 = *reinterpret_cast<const float4*>(p);
                    float4 o4;
                    o4.x = x4.x + rbeta * (a4[0] * scale);
                    o4.y = x4.y + rbeta * (a4[1] * scale);
                    o4.z = x4.z + rbeta * (a4[2] * scale);
                    o4.w = x4.w + rbeta * (a4[3] * scale);
                    *reinterpret_cast<float4*>(p) = o4;
                } else if (EPI == 2) {
                    ushort4 o4;
                    o4.x = f2b(gelu_f(a4[0] * scale));
                    o4.y = f2b(gelu_f(a4[1] * scale));
                    o4.z = f2b(gelu_f(a4[2] * scale));
                    o4.w = f2b(gelu_f(a4[3] * scale));
                    *reinterpret_cast<ushort4*>((u16*)C + (size_t)row * ldC + colb) = o4;
                } else {   // EPI == 3
                    int gc = coff + colb;
                    float* dst = (float*)C + (size_t)row * ldC + gc;
                    if (gc + 3 < cmax) {
                        float4 b4 = *reinterpret_cast<const float4*>(bias + gc);
                        float4 o4;
                        o4.x = (a4[0] + b4.x) * scale;
                        o4.y = (a4[1] + b4.y) * scale;
                        o4.z = (a4[2] + b4.z) * scale;
                        o4.w = (a4[3] + b4.w) * scale;
                        *reinterpret_cast<float4*>(dst) = o4;
                    } else {
                        #pragma unroll
                        for (int j = 0; j < 4; ++j)
                            if (gc + j < cmax) dst[j] = (a4[j] + bias[gc + j]) * scale;
                    }
                }
            }
        }
        return;
    }

    // EPI == 5, unswapped: col = lane&15 (n side), row = (lane>>4)*4+reg (m side)
    if (n0 < 2048) {
        int sq = wc >> 6;                    // 0 = q half, 1 = k half
        int head = n0 >> 7;
        const float* scp = sq ? ks : qs;
        const float* bip = sq ? kb : qb;
        u16* dst = (u16*)(sq ? C3 : C2);
        float scv[NF], biv[NF];
        #pragma unroll
        for (int n = 0; n < NF; ++n) { scv[n] = scp[n * 16 + fr]; biv[n] = bip[n * 16 + fr]; }
        #pragma unroll
        for (int m = 0; m < MF; ++m) {
            #pragma unroll
            for (int reg = 0; reg < 4; ++reg) {
                float v[NF]; float s1 = 0.f, s2 = 0.f;
                #pragma unroll
                for (int n = 0; n < NF; ++n) {
                    v[n] = acc[m][n][reg] * scale;
                    s1 += v[n]; s2 += v[n] * v[n];
                }
                #pragma unroll
                for (int off = 1; off < 16; off <<= 1) {
                    s1 += __shfl_xor(s1, off);
                    s2 += __shfl_xor(s2, off);
                }
                float mu = s1 * (1.f / 64.f);
                float var = s2 * (1.f / 64.f) - mu * mu;
                float rs = rsqrtf(var + 1e-6f);
                int row = m0 + wr + m * 16 + 4 * fg + reg;
                int bb = row >> 9, t = row & (TT - 1);
                size_t base = ((size_t)(bb * NH + head) * TT + t) * HD;
                #pragma unroll
                for (int n = 0; n < NF; ++n)
                    dst[base + n * 16 + fr] = f2b((v[n] - mu) * rs * scv[n] + biv[n]);
            }
        }
    } else {
        #pragma unroll
        for (int m = 0; m < MF; ++m) {
            int row0 = m0 + wr + m * 16 + 4 * fg;
            int bb = row0 >> 9, t0 = row0 & (TT - 1);
            #pragma unroll
            for (int n = 0; n < NF; ++n) {
                int colv = n0 - 2048 + wc + n * 16 + fr;
                int hh = colv >> 6, dd = colv & 63;
                ushort4 o4;
                o4.x = f2b(acc[m][n][0] * scale);
                o4.y = f2b(acc[m][n][1] * scale);
                o4.z = f2b(acc[m][n][2] * scale);
                o4.w = f2b(acc[m][n][3] * scale);
                *reinterpret_cast<ushort4*>((u16*)C +
                    (((size_t)(bb * NH + hh) * HD + dd) * TT + t0)) = o4;
            }
        }
    }
}

// Fused flash attention, k-split: per (qt, bh) block, 8 waves (512 thr).
// Wave (sub, half): sub = q-subtile (16 rows), half = kt parity. Both halves
// accumulate unnormalized partial sums (no max-sub => split-K is exact);
// combine via LDS, then normalize.
__global__ __launch_bounds__(512) void attn_k(const u16* __restrict__ qh,
        const u16* __restrict__ kh, const u16* __restrict__ vt,
        u16* __restrict__ ob) {
    int qt = blockIdx.x, bh = blockIdx.y;
    int b = bh >> 4, hh = bh & 15;
    int tid = threadIdx.x;
    int w = tid >> 6, lam = tid & 63;
    int sub = w & 3, half = w >> 2;
    int fr = lam & 15, fg = lam >> 4;
    __shared__ __align__(16) u16 ps[8][16 * 64];   // per-wave P tile, XOR-swizzled
    __shared__ __align__(16) f32x4 comb[4][64][5]; // half-0 partials: oacc[4] + rsum
    u16* pw = ps[w];
    const u16* qbase = qh + ((size_t)bh * TT + qt * 64 + sub * 16) * HD;
    bf16x8 af0 = *reinterpret_cast<const bf16x8*>(qbase + (size_t)fr * HD + fg * 8);
    bf16x8 af1 = *reinterpret_cast<const bf16x8*>(qbase + (size_t)fr * HD + 32 + fg * 8);
    f32x4 oacc[4];
    #pragma unroll
    for (int n = 0; n < 4; ++n) oacc[n] = (f32x4)0.0f;
    float rsum[4] = {0.f, 0.f, 0.f, 0.f};
    const u16* vbh = vt + (size_t)bh * HD * TT;
    for (int kt = half; kt <= qt; kt += 2) {
        const u16* kbase = kh + ((size_t)bh * TT + kt * 64) * HD;
        bool diag = (kt == qt);
        #pragma unroll
        for (int n = 0; n < 4; ++n) {
            bf16x8 b0 = *reinterpret_cast<const bf16x8*>(kbase + (size_t)(n * 16 + fr) * HD + fg * 8);
            bf16x8 b1 = *reinterpret_cast<const bf16x8*>(kbase + (size_t)(n * 16 + fr) * HD + 32 + fg * 8);
            f32x4 s = (f32x4)0.0f;
            s = __builtin_amdgcn_mfma_f32_16x16x32_bf16(af0, b0, s, 0, 0, 0);
            s = __builtin_amdgcn_mfma_f32_16x16x32_bf16(af1, b1, s, 0, 0, 0);
            #pragma unroll
            for (int reg = 0; reg < 4; ++reg) {
                int row = fg * 4 + reg;            // q-local within sub-tile
                int col = n * 16 + fr;             // k-local (0..63)
                float p = 0.f;
                if (!diag || col <= (sub * 16 + row)) p = __expf(s[reg] * (1.f / 64.f));
                rsum[reg] += p;
                int chunk = col >> 3;
                int off = row * 128 + (((chunk ^ (row & 7)) << 4) | ((col & 7) << 1));
                *reinterpret_cast<u16*>((char*)pw + off) = f2b(p);
            }
        }
        bf16x8 pa0, pa1;
        {
            int c0 = 0 * 4 + fg, c1 = 1 * 4 + fg;
            pa0 = *reinterpret_cast<const bf16x8*>((char*)pw + fr * 128 + ((c0 ^ (fr & 7)) << 4));
            pa1 = *reinterpret_cast<const bf16x8*>((char*)pw + fr * 128 + ((c1 ^ (fr & 7)) << 4));
        }
        #pragma unroll
        for (int n = 0; n < 4; ++n) {
            const u16* vb = vbh + (size_t)(n * 16 + fr) * TT + kt * 64;
            bf16x8 v0 = *reinterpret_cast<const bf16x8*>(vb + fg * 8);
            bf16x8 v1 = *reinterpret_cast<const bf16x8*>(vb + 32 + fg * 8);
            oacc[n] = __builtin_amdgcn_mfma_f32_16x16x32_bf16(pa0, v0, oacc[n], 0, 0, 0);
            oacc[n] = __builtin_amdgcn_mfma_f32_16x16x32_bf16(pa1, v1, oacc[n], 0, 0, 0);
        }
    }
    // combine halves: half-0 publishes partials, half-1 finishes
    if (half == 0) {
        #pragma unroll
        for (int n = 0; n < 4; ++n) comb[sub][lam][n] = oacc[n];
        f32x4 r4 = {rsum[0], rsum[1], rsum[2], rsum[3]};
        comb[sub][lam][4] = r4;
    }
    __syncthreads();
    if (half == 1) {
        #pragma unroll
        for (int n = 0; n < 4; ++n) oacc[n] += comb[sub][lam][n];
        f32x4 r4 = comb[sub][lam][4];
        rsum[0] += r4[0]; rsum[1] += r4[1]; rsum[2] += r4[2]; rsum[3] += r4[3];
        #pragma unroll
        for (int reg = 0; reg < 4; ++reg) {
            float r = rsum[reg];
            r += __shfl_xor(r, 1); r += __shfl_xor(r, 2);
            r += __shfl_xor(r, 4); r += __shfl_xor(r, 8);
            rsum[reg] = 1.f / r;
        }
        int tbase = b * TT + qt * 64 + sub * 16 + fg * 4;
        #pragma unroll
        for (int n = 0; n < 4; ++n) {
            int dcol = hh * 64 + n * 16 + fr;
            #pragma unroll
            for (int reg = 0; reg < 4; ++reg)
                ob[(size_t)(tbase + reg) * NN + dcol] = f2b(oacc[n][reg] * rsum[reg]);
        }
    }
}

extern "C" void kernel_launch(void* const* d_in, const int* in_sizes, int n_in,
                              void* d_out, int out_size, void* d_ws, size_t ws_size,
                              hipStream_t stream) {
    (void)in_sizes; (void)n_in; (void)out_size;
    const int*   tok  = (const int*)d_in[0];
    const float* emb  = (const float*)d_in[1];
    const float* pos  = (const float*)d_in[2];
    const float* ln1s = (const float*)d_in[3];
    const float* ln1b = (const float*)d_in[4];
    const float* qkW  = (const float*)d_in[5];
    const float* vW   = (const float*)d_in[6];
    const float* oW   = (const float*)d_in[7];
    const float* qns  = (const float*)d_in[8];
    const float* qnb  = (const float*)d_in[9];
    const float* kns  = (const float*)d_in[10];
    const float* knb  = (const float*)d_in[11];
    const float* ln2s = (const float*)d_in[12];
    const float* ln2b = (const float*)d_in[13];
    const float* W1   = (const float*)d_in[14];
    const float* W2   = (const float*)d_in[15];
    const float* lnfs = (const float*)d_in[16];
    const float* lnfb = (const float*)d_in[17];
    const float* outW = (const float*)d_in[18];
    const float* outb = (const float*)d_in[19];
    float* out = (float*)d_out;

    const float inv32 = 0.03125f;       // 1/sqrt(N)
    const float betaD = 1.f / 12.f;     // BETA / D
    const size_t LSTRIDE = (size_t)6144 * 1024;       // per-layer Wt elements
    const int NPADV = (VV + 127) & ~127;              // 50304

    // Acts: x f32 4MB | h 2MB | mid 2MB | qh 2MB | kh 2MB | vt 2MB | ob 2MB = 16MB
    char* p = (char*)d_ws;
    float* x   = (float*)p;   p += (size_t)4 << 20;
    u16*   h   = (u16*)p;     p += (size_t)2 << 20;
    u16*   mid = (u16*)p;     p += (size_t)2 << 20;
    u16*   qh  = (u16*)p;     p += (size_t)2 << 20;
    u16*   kh  = (u16*)p;     p += (size_t)2 << 20;
    u16*   vt  = (u16*)p;     p += (size_t)2 << 20;
    u16*   ob  = (u16*)p;     p += (size_t)2 << 20;

    // big path: WtAll 144MB (12 layers) + WtL 50304x1024 bf16 (~98.3MB) => 264MB total
    bool big = ws_size >= ((size_t)264 << 20);
    u16* WtAll = (u16*)p;     // big: 144MB; small: 12MB single-layer buffer
    u16* WtL;
    if (big) {
        WtL = WtAll + (size_t)12 * LSTRIDE;
    } else {
        WtL = WtAll + LSTRIDE;            // 32MB chunk buffer (16384 cols)
    }

    embed_k<<<1024, 256, 0, stream>>>(tok, emb, pos, x);
    if (big) {
        // all 60 weight transposes in one launch
        transpose5_k<<<dim3(32, 16, 60), 256, 0, stream>>>(qkW, vW, oW, W1, W2,
                WtAll, 0, LSTRIDE);
        // full outW transpose (padded rows zero-filled)
        transpose_k<<<dim3(NPADV / 64, 16), 256, 0, stream>>>(outW, WtL, VV, VV, NN);
    }

    for (int l = 0; l < NL; ++l) {
        const u16* WtB = big ? WtAll + (size_t)l * LSTRIDE : WtAll;
        ln_k<1><<<1024, 256, 0, stream>>>(x, h, ln1s + l * NN, ln1b + l * NN);
        if (!big) {
            transpose5_k<<<dim3(32, 16, 5), 256, 0, stream>>>(qkW, vW, oW, W1, W2,
                    WtAll, l, 0);
        }
        // Fused QKV projection + per-head LN + V^T store (768 blocks, 3/CU)
        gemm_k<32,128,5><<<dim3(24, 32), 256, 0, stream>>>(h, WtB, vt, qh, kh,
                nullptr, qns + l * HD, qnb + l * HD, kns + l * HD, knb + l * HD,
                NN, 0, 0, 0, inv32, 0.f);
        // Fused attention (k-split, 512 threads)
        attn_k<<<dim3(8, 32), 512, 0, stream>>>(qh, kh, vt, ob);
        // Output projection + residual (512 blocks, 2/CU)
        gemm_k<32,64,1><<<dim3(16, 32), 256, 0, stream>>>(ob, WtB + (size_t)3072 * 1024,
                x, nullptr, nullptr, nullptr, nullptr, nullptr, nullptr, nullptr,
                NN, NN, 0, 0, inv32, betaD);
        // MLP
        ln_k<1><<<1024, 256, 0, stream>>>(x, h, ln2s + l * NN, ln2b + l * NN);
        gemm_k<32,64,2><<<dim3(16, 32), 256, 0, stream>>>(h, WtB + (size_t)4096 * 1024,
                mid, nullptr, nullptr, nullptr, nullptr, nullptr, nullptr, nullptr,
                NN, NN, 0, 0, inv32, 0.f);
        gemm_k<32,64,1><<<dim3(16, 32), 256, 0, stream>>>(mid, WtB + (size_t)5120 * 1024,
                x, nullptr, nullptr, nullptr, nullptr, nullptr, nullptr, nullptr,
                NN, NN, 0, 0, inv32, betaD);
    }
    ln_k<0><<<1024, 256, 0, stream>>>(x, h, lnfs, lnfb);

    if (big) {
        // one logits GEMM, xcd-grouped 1D grid: all 8 m-tiles of a panel on one XCD
        gemm_k<128,128,3,1><<<dim3(NPADV / 128 * 8), 256, 0, stream>>>(h, WtL, out,
                nullptr, nullptr, outb, nullptr, nullptr, nullptr, nullptr,
                NN, VV, 0, VV, inv32, 0.f);
    } else {
        for (int c0 = 0; c0 < VV; c0 += 16384) {
            int cn = VV - c0; if (cn > 16384) cn = 16384;
            int npad = (cn + 127) & ~127;
            transpose_k<<<dim3(npad / 64, 16), 256, 0, stream>>>(outW + c0, WtL, cn, VV, NN);
            gemm_k<128,128,3,1><<<dim3(npad / 128 * 8), 256, 0, stream>>>(h, WtL, out,
                    nullptr, nullptr, outb, nullptr, nullptr, nullptr, nullptr,
                    NN, VV, c0, VV, inv32, 0.f);
        }
    }
}

// Round 17
// 1184.357 us; speedup vs baseline: 2.3436x; 1.2192x over previous
//
#include <hip/hip_runtime.h>
#include <hip/hip_bf16.h>

// Model constants
#define TT 512
#define NN 1024
#define NH 16
#define HD 64
#define NL 12
#define VV 50257

typedef unsigned short u16;
typedef short bf16x8 __attribute__((ext_vector_type(8)));
typedef float f32x4 __attribute__((ext_vector_type(4)));

struct TrJob { const float* src; u16* dst; int ncols; int ldw; int ntiles; int tbase; };
struct TrPack { TrJob j[3]; };

__device__ __forceinline__ float gelu_f(float x) {
    float x3 = x * x * x;
    return 0.5f * x * (1.0f + tanhf(0.7978845608028654f * (x + 0.044715f * x3)));
}

// fp32 -> bf16 RNE (finite inputs only)
__device__ __forceinline__ u16 f2b(float f) {
    unsigned int u = __float_as_uint(f);
    return (u16)((u + 0x7FFFu + ((u >> 16) & 1u)) >> 16);
}

// async global->LDS, 16B per lane; LDS dest is wave-uniform base + lane*16
__device__ __forceinline__ void gload16(const void* g, void* l) {
    __builtin_amdgcn_global_load_lds(
        (const __attribute__((address_space(1))) unsigned int*)g,
        (__attribute__((address_space(3))) unsigned int*)l,
        16, 0, 0);
}

// x[row,:] = 1024*emb[tok[row],:] + 32*pos[t,:]
__global__ __launch_bounds__(256) void embed_k(const int* __restrict__ tok,
        const float* __restrict__ emb, const float* __restrict__ pos,
        float* __restrict__ x) {
    int row = blockIdx.x;
    int t = row & (TT - 1);
    int tk = tok[row];
    int c = threadIdx.x * 4;
    float4 e = *reinterpret_cast<const float4*>(emb + (size_t)tk * NN + c);
    float4 p = *reinterpret_cast<const float4*>(pos + (size_t)t * NN + c);
    float4 o;
    o.x = 1024.f * e.x + 32.f * p.x;
    o.y = 1024.f * e.y + 32.f * p.y;
    o.z = 1024.f * e.z + 32.f * p.z;
    o.w = 1024.f * e.w + 32.f * p.w;
    *reinterpret_cast<float4*>(x + (size_t)row * NN + c) = o;
}

// Row LayerNorm over N=1024 (+ optional gelu), bf16 output
template<int ACT>
__global__ __launch_bounds__(256) void ln_k(const float* __restrict__ in,
        u16* __restrict__ out, const float* __restrict__ sc, const float* __restrict__ bi) {
    int row = blockIdx.x;
    const float* r = in + (size_t)row * NN;
    int tid = threadIdx.x;
    float v[4]; float s1 = 0.f, s2 = 0.f;
    #pragma unroll
    for (int i = 0; i < 4; ++i) { v[i] = r[tid + i * 256]; s1 += v[i]; s2 += v[i] * v[i]; }
    #pragma unroll
    for (int off = 32; off > 0; off >>= 1) { s1 += __shfl_xor(s1, off); s2 += __shfl_xor(s2, off); }
    __shared__ float red[8];
    __shared__ float st[2];
    int wid = tid >> 6;
    if ((tid & 63) == 0) { red[wid] = s1; red[4 + wid] = s2; }
    __syncthreads();
    if (tid == 0) {
        float a = red[0] + red[1] + red[2] + red[3];
        float b = red[4] + red[5] + red[6] + red[7];
        float mu = a * (1.f / NN);
        float var = b * (1.f / NN) - mu * mu;
        st[0] = mu; st[1] = rsqrtf(var + 1e-6f);
    }
    __syncthreads();
    float mu = st[0], rs = st[1];
    u16* o = out + (size_t)row * NN;
    #pragma unroll
    for (int i = 0; i < 4; ++i) {
        int c = tid + i * 256;
        float y = (v[i] - mu) * rs * sc[c] + bi[c];
        if (ACT) y = gelu_f(y);
        o[c] = f2b(y);
    }
}

// Per-layer weight transpose (upfront, layer l0 only): z selects which of 5.
__global__ __launch_bounds__(256) void transpose5_k(const float* __restrict__ qkW,
        const float* __restrict__ vW, const float* __restrict__ oW,
        const float* __restrict__ W1, const float* __restrict__ W2,
        u16* __restrict__ Wt, int l0, size_t lstride) {
    int z = blockIdx.z + l0 * 5;
    int l = z / 5, which = z - l * 5;
    const float* W; int Ncols; size_t doff;
    switch (which) {
      case 0:  W = qkW + (size_t)l * NN * 2048; Ncols = 2048; doff = 0; break;
      case 1:  W = vW + (size_t)l * NN * NN;  Ncols = 1024; doff = (size_t)2048 * 1024; break;
      case 2:  W = oW + (size_t)l * NN * NN;  Ncols = 1024; doff = (size_t)3072 * 1024; break;
      case 3:  W = W1 + (size_t)l * NN * NN;  Ncols = 1024; doff = (size_t)4096 * 1024; break;
      default: W = W2 + (size_t)l * NN * NN;  Ncols = 1024; doff = (size_t)5120 * 1024; break;
    }
    int n0 = blockIdx.x * 64;
    if (n0 >= Ncols) return;
    int k0 = blockIdx.y * 64;
    u16* dst = Wt + (size_t)l * lstride + doff;
    __shared__ float t[64][65];
    int tid = threadIdx.x;
    #pragma unroll
    for (int j = 0; j < 4; ++j) {
        int e = tid + j * 256;
        int kr = e >> 4, nc = (e & 15) * 4;
        float4 v = *reinterpret_cast<const float4*>(W + (size_t)(k0 + kr) * Ncols + n0 + nc);
        t[kr][nc + 0] = v.x; t[kr][nc + 1] = v.y; t[kr][nc + 2] = v.z; t[kr][nc + 3] = v.w;
    }
    __syncthreads();
    #pragma unroll
    for (int j = 0; j < 4; ++j) {
        int e = tid + j * 256;
        int nr = e >> 4, kc = (e & 15) * 4;
        ushort4 o;
        o.x = f2b(t[kc + 0][nr]);
        o.y = f2b(t[kc + 1][nr]);
        o.z = f2b(t[kc + 2][nr]);
        o.w = f2b(t[kc + 3][nr]);
        *reinterpret_cast<ushort4*>(dst + (size_t)(n0 + nr) * 1024 + k0 + kc) = o;
    }
}

// Guarded single transpose (small-path fallback): fp32 [K][Ncols] -> bf16 [Npad][K]
__global__ __launch_bounds__(256) void transpose_k(const float* __restrict__ W,
        u16* __restrict__ Wt, int Ncols, int ldW, int K) {
    __shared__ float t[64][65];
    int n0 = blockIdx.x * 64, k0 = blockIdx.y * 64;
    int tid = threadIdx.x;
    #pragma unroll
    for (int j = 0; j < 4; ++j) {
        int e = tid + j * 256;
        int kr = e >> 4, nc = (e & 15) * 4;
        int n = n0 + nc;
        float4 v = {0.f, 0.f, 0.f, 0.f};
        if (n + 3 < Ncols) {
            v = *reinterpret_cast<const float4*>(W + (size_t)(k0 + kr) * ldW + n);
        } else {
            if (n + 0 < Ncols) v.x = W[(size_t)(k0 + kr) * ldW + n + 0];
            if (n + 1 < Ncols) v.y = W[(size_t)(k0 + kr) * ldW + n + 1];
            if (n + 2 < Ncols) v.z = W[(size_t)(k0 + kr) * ldW + n + 2];
        }
        t[kr][nc + 0] = v.x; t[kr][nc + 1] = v.y; t[kr][nc + 2] = v.z; t[kr][nc + 3] = v.w;
    }
    __syncthreads();
    #pragma unroll
    for (int j = 0; j < 4; ++j) {
        int e = tid + j * 256;
        int nr = e >> 4, kc = (e & 15) * 4;
        ushort4 o;
        o.x = f2b(t[kc + 0][nr]);
        o.y = f2b(t[kc + 1][nr]);
        o.z = f2b(t[kc + 2][nr]);
        o.w = f2b(t[kc + 3][nr]);
        *reinterpret_cast<ushort4*>(Wt + (size_t)(n0 + nr) * K + k0 + kc) = o;
    }
}

// swizzled LDS fragment read: row r, logical 16B chunk c
__device__ __forceinline__ bf16x8 ldsfrag(const u16* base, int r, int c) {
    int off = r * 64 + ((c ^ (r & 7)) << 3);
    return *reinterpret_cast<const bf16x8*>(base + off);
}

// MFMA GEMM, TMxTN tile, BK=64, SINGLE-buffer LDS (m97 structure).
// 1D grid: blocks [0,nGemm) do GEMM (n0=(id%NX)*TN, m0=(id/NX)*TM); blocks
// [nGemm,..) execute absorbed 64x64 weight-transpose tiles from TrPack
// (next layer's weights / outW chunks — stream order guarantees visibility).
// XCDMAP=1: logits mapping (all 8 m-tiles of a B-panel on SAME XCD), no filler.
// EPI 1/2 use SWAPPED mfma operands -> float4/ushort4 epilogue.
// EPI 3 UNSWAPPED (64B-contiguous quarter-wave store segments beat 16B scatter).
// EPI 5: fused QKV (unswapped): per-head LN -> qh/kh; V^T -> vt.
template<int TM, int TN, int EPI, int XCDMAP = 0>
__global__ __launch_bounds__(256) void gemm_k(const u16* __restrict__ A,
        const u16* __restrict__ Bt, void* __restrict__ C,
        void* __restrict__ C2, void* __restrict__ C3,
        const float* __restrict__ bias,
        const float* __restrict__ qs, const float* __restrict__ qb,
        const float* __restrict__ ks, const float* __restrict__ kb,
        int K, int ldC, int coff, int cmax, float scale, float rbeta,
        int nGemm, int NX, TrPack trp) {
    constexpr int MF = TM / 32, NF = TN / 32;     // frags per wave
    constexpr int IA = TM / 8, IB = TN / 8;       // 1KB staging issues
    constexpr bool SW = (EPI == 1 || EPI == 2);   // swapped operand order
    constexpr int GB = (TM + TN) * 128;           // gemm LDS bytes
    constexpr int SB = (GB > 16640) ? GB : 16640; // union with transpose tile
    __shared__ __align__(16) char smem[SB];
    u16* As = (u16*)smem;
    u16* Bs = As + TM * 64;
    int tid = threadIdx.x;
    int lam = tid & 63, w = tid >> 6;
    int m0, n0;
    if (XCDMAP) {
        int i = blockIdx.x;
        int per = gridDim.x >> 3;          // jobs per XCD
        int j = (i & 7) * per + (i >> 3);  // xcd-grouped job id
        m0 = (j & 7) * TM;                 // 8 m-tiles cycle fastest
        n0 = (j >> 3) * TN;                // consecutive panels per XCD
    } else {
        int id = blockIdx.x;
        if (id >= nGemm) {
            // absorbed transpose tile
            int ex = id - nGemm;
            const float* src = nullptr; u16* dst = nullptr;
            int ncols = 0, ldw = 0, tno = 0;
            #pragma unroll
            for (int jj = 0; jj < 3; ++jj) {
                int nt = trp.j[jj].ntiles;
                if (src == nullptr && ex < nt) {
                    src = trp.j[jj].src; dst = trp.j[jj].dst;
                    ncols = trp.j[jj].ncols; ldw = trp.j[jj].ldw;
                    tno = trp.j[jj].tbase + ex;
                }
                if (src == nullptr) ex -= nt;
            }
            if (src) {
                int ntx = (ncols + 63) >> 6;
                int tn0 = (tno % ntx) * 64, tk0 = (tno / ntx) * 64;
                float (*t)[65] = (float (*)[65])smem;
                #pragma unroll
                for (int j = 0; j < 4; ++j) {
                    int e = tid + j * 256;
                    int kr = e >> 4, nc = (e & 15) * 4;
                    int n = tn0 + nc;
                    float4 v = {0.f, 0.f, 0.f, 0.f};
                    if (n + 3 < ncols) {
                        v = *reinterpret_cast<const float4*>(src + (size_t)(tk0 + kr) * ldw + n);
                    } else {
                        if (n + 0 < ncols) v.x = src[(size_t)(tk0 + kr) * ldw + n + 0];
                        if (n + 1 < ncols) v.y = src[(size_t)(tk0 + kr) * ldw + n + 1];
                        if (n + 2 < ncols) v.z = src[(size_t)(tk0 + kr) * ldw + n + 2];
                    }
                    t[kr][nc + 0] = v.x; t[kr][nc + 1] = v.y;
                    t[kr][nc + 2] = v.z; t[kr][nc + 3] = v.w;
                }
                __syncthreads();
                #pragma unroll
                for (int j = 0; j < 4; ++j) {
                    int e = tid + j * 256;
                    int nr = e >> 4, kc = (e & 15) * 4;
                    ushort4 o;
                    o.x = f2b(t[kc + 0][nr]);
                    o.y = f2b(t[kc + 1][nr]);
                    o.z = f2b(t[kc + 2][nr]);
                    o.w = f2b(t[kc + 3][nr]);
                    *reinterpret_cast<ushort4*>(dst + (size_t)(tn0 + nr) * 1024 + tk0 + kc) = o;
                }
            }
            return;
        }
        m0 = (id / NX) * TM;
        n0 = (id % NX) * TN;
    }
    int lr = lam >> 3;              // row-in-8 within a 1KB issue
    int lc = (lam & 7) ^ lr;        // inverse-swizzled logical chunk
    const u16* Abase = A + (size_t)m0 * K;
    const u16* Bbase = Bt + (size_t)n0 * K;
    int wr = (w >> 1) * (TM / 2), wc = (w & 1) * (TN / 2);
    int fr = lam & 15, fg = lam >> 4;
    f32x4 acc[MF][NF];
    #pragma unroll
    for (int i = 0; i < MF; ++i)
        #pragma unroll
        for (int j = 0; j < NF; ++j) acc[i][j] = (f32x4)0.0f;

    for (int k0 = 0; k0 < K; k0 += 64) {
        #pragma unroll
        for (int i = 0; i < IA / 4; ++i) {
            int q = w * (IA / 4) + i;
            int r = q * 8 + lr;
            gload16(Abase + (size_t)r * K + k0 + lc * 8, (char*)As + q * 1024);
        }
        #pragma unroll
        for (int i = 0; i < IB / 4; ++i) {
            int q = w * (IB / 4) + i;
            int r = q * 8 + lr;
            gload16(Bbase + (size_t)r * K + k0 + lc * 8, (char*)Bs + q * 1024);
        }
        __syncthreads();                   // drains vmcnt(0) + barrier
        #pragma unroll
        for (int s = 0; s < 2; ++s) {
            bf16x8 af[MF], bfv[NF];
            #pragma unroll
            for (int m = 0; m < MF; ++m) af[m] = ldsfrag(As, wr + m * 16 + fr, s * 4 + fg);
            #pragma unroll
            for (int n = 0; n < NF; ++n) bfv[n] = ldsfrag(Bs, wc + n * 16 + fr, s * 4 + fg);
            #pragma unroll
            for (int m = 0; m < MF; ++m)
                #pragma unroll
                for (int n = 0; n < NF; ++n) {
                    if (SW)
                        acc[m][n] = __builtin_amdgcn_mfma_f32_16x16x32_bf16(bfv[n], af[m], acc[m][n], 0, 0, 0);
                    else
                        acc[m][n] = __builtin_amdgcn_mfma_f32_16x16x32_bf16(af[m], bfv[n], acc[m][n], 0, 0, 0);
                }
        }
        if (k0 + 64 < K) __syncthreads();  // protect LDS overwrite
    }

    if constexpr (SW) {
        // Swapped: C row = m0+wr+m*16+fr, cols = n0+wc+n*16+4*fg+{0..3}
        #pragma unroll
        for (int m = 0; m < MF; ++m) {
            int row = m0 + wr + m * 16 + fr;
            #pragma unroll
            for (int n = 0; n < NF; ++n) {
                int colb = n0 + wc + n * 16 + 4 * fg;
                f32x4 a4 = acc[m][n];
                if (EPI == 1) {
                    float* p = (float*)C + (size_t)row * ldC + colb;
                    float4 x4 = *reinterpret_cast<const float4*>(p);
                    float4 o4;
                    o4.x = x4.x + rbeta * (a4[0] * scale);
                    o4.y = x4.y + rbeta * (a4[1] * scale);
                    o4.z = x4.z + rbeta * (a4[2] * scale);
                    o4.w = x4.w + rbeta * (a4[3] * scale);
                    *reinterpret_cast<float4*>(p) = o4;
                } else {
                    ushort4 o4;
                    o4.x = f2b(gelu_f(a4[0] * scale));
                    o4.y = f2b(gelu_f(a4[1] * scale));
                    o4.z = f2b(gelu_f(a4[2] * scale));
                    o4.w = f2b(gelu_f(a4[3] * scale));
                    *reinterpret_cast<ushort4*>((u16*)C + (size_t)row * ldC + colb) = o4;
                }
            }
        }
        return;
    }

    // Unswapped: col = lane&15 (n side), row = (lane>>4)*4+reg (m side)
    if constexpr (EPI == 3) {
        #pragma unroll
        for (int m = 0; m < MF; ++m) {
            #pragma unroll
            for (int n = 0; n < NF; ++n) {
                int ncol = n0 + wc + n * 16 + fr;
                int mrow = m0 + wr + m * 16 + 4 * fg;
                #pragma unroll
                for (int reg = 0; reg < 4; ++reg) {
                    int row = mrow + reg;
                    int gc = coff + ncol;
                    if (gc < cmax)
                        ((float*)C)[(size_t)row * ldC + gc] = (acc[m][n][reg] + bias[gc]) * scale;
                }
            }
        }
        return;
    }
    // EPI == 5
    if (n0 < 2048) {
        int sq = wc >> 6;                    // 0 = q half, 1 = k half
        int head = n0 >> 7;
        const float* scp = sq ? ks : qs;
        const float* bip = sq ? kb : qb;
        u16* dst = (u16*)(sq ? C3 : C2);
        float scv[NF], biv[NF];
        #pragma unroll
        for (int n = 0; n < NF; ++n) { scv[n] = scp[n * 16 + fr]; biv[n] = bip[n * 16 + fr]; }
        #pragma unroll
        for (int m = 0; m < MF; ++m) {
            #pragma unroll
            for (int reg = 0; reg < 4; ++reg) {
                float v[NF]; float s1 = 0.f, s2 = 0.f;
                #pragma unroll
                for (int n = 0; n < NF; ++n) {
                    v[n] = acc[m][n][reg] * scale;
                    s1 += v[n]; s2 += v[n] * v[n];
                }
                #pragma unroll
                for (int off = 1; off < 16; off <<= 1) {
                    s1 += __shfl_xor(s1, off);
                    s2 += __shfl_xor(s2, off);
                }
                float mu = s1 * (1.f / 64.f);
                float var = s2 * (1.f / 64.f) - mu * mu;
                float rs = rsqrtf(var + 1e-6f);
                int row = m0 + wr + m * 16 + 4 * fg + reg;
                int bb = row >> 9, t = row & (TT - 1);
                size_t base = ((size_t)(bb * NH + head) * TT + t) * HD;
                #pragma unroll
                for (int n = 0; n < NF; ++n)
                    dst[base + n * 16 + fr] = f2b((v[n] - mu) * rs * scv[n] + biv[n]);
            }
        }
    } else {
        #pragma unroll
        for (int m = 0; m < MF; ++m) {
            int row0 = m0 + wr + m * 16 + 4 * fg;
            int bb = row0 >> 9, t0 = row0 & (TT - 1);
            #pragma unroll
            for (int n = 0; n < NF; ++n) {
                int colv = n0 - 2048 + wc + n * 16 + fr;
                int hh = colv >> 6, dd = colv & 63;
                ushort4 o4;
                o4.x = f2b(acc[m][n][0] * scale);
                o4.y = f2b(acc[m][n][1] * scale);
                o4.z = f2b(acc[m][n][2] * scale);
                o4.w = f2b(acc[m][n][3] * scale);
                *reinterpret_cast<ushort4*>((u16*)C +
                    (((size_t)(bb * NH + hh) * HD + dd) * TT + t0)) = o4;
            }
        }
    }
}

// Fused flash attention, k-split: per (qt, bh) block, 8 waves (512 thr).
__global__ __launch_bounds__(512) void attn_k(const u16* __restrict__ qh,
        const u16* __restrict__ kh, const u16* __restrict__ vt,
        u16* __restrict__ ob) {
    int qt = blockIdx.x, bh = blockIdx.y;
    int b = bh >> 4, hh = bh & 15;
    int tid = threadIdx.x;
    int w = tid >> 6, lam = tid & 63;
    int sub = w & 3, half = w >> 2;
    int fr = lam & 15, fg = lam >> 4;
    __shared__ __align__(16) u16 ps[8][16 * 64];   // per-wave P tile, XOR-swizzled
    __shared__ __align__(16) f32x4 comb[4][64][5]; // half-0 partials: oacc[4] + rsum
    u16* pw = ps[w];
    const u16* qbase = qh + ((size_t)bh * TT + qt * 64 + sub * 16) * HD;
    bf16x8 af0 = *reinterpret_cast<const bf16x8*>(qbase + (size_t)fr * HD + fg * 8);
    bf16x8 af1 = *reinterpret_cast<const bf16x8*>(qbase + (size_t)fr * HD + 32 + fg * 8);
    f32x4 oacc[4];
    #pragma unroll
    for (int n = 0; n < 4; ++n) oacc[n] = (f32x4)0.0f;
    float rsum[4] = {0.f, 0.f, 0.f, 0.f};
    const u16* vbh = vt + (size_t)bh * HD * TT;
    for (int kt = half; kt <= qt; kt += 2) {
        const u16* kbase = kh + ((size_t)bh * TT + kt * 64) * HD;
        bool diag = (kt == qt);
        #pragma unroll
        for (int n = 0; n < 4; ++n) {
            bf16x8 b0 = *reinterpret_cast<const bf16x8*>(kbase + (size_t)(n * 16 + fr) * HD + fg * 8);
            bf16x8 b1 = *reinterpret_cast<const bf16x8*>(kbase + (size_t)(n * 16 + fr) * HD + 32 + fg * 8);
            f32x4 s = (f32x4)0.0f;
            s = __builtin_amdgcn_mfma_f32_16x16x32_bf16(af0, b0, s, 0, 0, 0);
            s = __builtin_amdgcn_mfma_f32_16x16x32_bf16(af1, b1, s, 0, 0, 0);
            #pragma unroll
            for (int reg = 0; reg < 4; ++reg) {
                int row = fg * 4 + reg;            // q-local within sub-tile
                int col = n * 16 + fr;             // k-local (0..63)
                float p = 0.f;
                if (!diag || col <= (sub * 16 + row)) p = __expf(s[reg] * (1.f / 64.f));
                rsum[reg] += p;
                int chunk = col >> 3;
                int off = row * 128 + (((chunk ^ (row & 7)) << 4) | ((col & 7) << 1));
                *reinterpret_cast<u16*>((char*)pw + off) = f2b(p);
            }
        }
        bf16x8 pa0, pa1;
        {
            int c0 = 0 * 4 + fg, c1 = 1 * 4 + fg;
            pa0 = *reinterpret_cast<const bf16x8*>((char*)pw + fr * 128 + ((c0 ^ (fr & 7)) << 4));
            pa1 = *reinterpret_cast<const bf16x8*>((char*)pw + fr * 128 + ((c1 ^ (fr & 7)) << 4));
        }
        #pragma unroll
        for (int n = 0; n < 4; ++n) {
            const u16* vb = vbh + (size_t)(n * 16 + fr) * TT + kt * 64;
            bf16x8 v0 = *reinterpret_cast<const bf16x8*>(vb + fg * 8);
            bf16x8 v1 = *reinterpret_cast<const bf16x8*>(vb + 32 + fg * 8);
            oacc[n] = __builtin_amdgcn_mfma_f32_16x16x32_bf16(pa0, v0, oacc[n], 0, 0, 0);
            oacc[n] = __builtin_amdgcn_mfma_f32_16x16x32_bf16(pa1, v1, oacc[n], 0, 0, 0);
        }
    }
    if (half == 0) {
        #pragma unroll
        for (int n = 0; n < 4; ++n) comb[sub][lam][n] = oacc[n];
        f32x4 r4 = {rsum[0], rsum[1], rsum[2], rsum[3]};
        comb[sub][lam][4] = r4;
    }
    __syncthreads();
    if (half == 1) {
        #pragma unroll
        for (int n = 0; n < 4; ++n) oacc[n] += comb[sub][lam][n];
        f32x4 r4 = comb[sub][lam][4];
        rsum[0] += r4[0]; rsum[1] += r4[1]; rsum[2] += r4[2]; rsum[3] += r4[3];
        #pragma unroll
        for (int reg = 0; reg < 4; ++reg) {
            float r = rsum[reg];
            r += __shfl_xor(r, 1); r += __shfl_xor(r, 2);
            r += __shfl_xor(r, 4); r += __shfl_xor(r, 8);
            rsum[reg] = 1.f / r;
        }
        int tbase = b * TT + qt * 64 + sub * 16 + fg * 4;
        #pragma unroll
        for (int n = 0; n < 4; ++n) {
            int dcol = hh * 64 + n * 16 + fr;
            #pragma unroll
            for (int reg = 0; reg < 4; ++reg)
                ob[(size_t)(tbase + reg) * NN + dcol] = f2b(oacc[n][reg] * rsum[reg]);
        }
    }
}

extern "C" void kernel_launch(void* const* d_in, const int* in_sizes, int n_in,
                              void* d_out, int out_size, void* d_ws, size_t ws_size,
                              hipStream_t stream) {
    (void)in_sizes; (void)n_in; (void)out_size;
    const int*   tok  = (const int*)d_in[0];
    const float* emb  = (const float*)d_in[1];
    const float* pos  = (const float*)d_in[2];
    const float* ln1s = (const float*)d_in[3];
    const float* ln1b = (const float*)d_in[4];
    const float* qkW  = (const float*)d_in[5];
    const float* vW   = (const float*)d_in[6];
    const float* oW   = (const float*)d_in[7];
    const float* qns  = (const float*)d_in[8];
    const float* qnb  = (const float*)d_in[9];
    const float* kns  = (const float*)d_in[10];
    const float* knb  = (const float*)d_in[11];
    const float* ln2s = (const float*)d_in[12];
    const float* ln2b = (const float*)d_in[13];
    const float* W1   = (const float*)d_in[14];
    const float* W2   = (const float*)d_in[15];
    const float* lnfs = (const float*)d_in[16];
    const float* lnfb = (const float*)d_in[17];
    const float* outW = (const float*)d_in[18];
    const float* outb = (const float*)d_in[19];
    float* out = (float*)d_out;

    const float inv32 = 0.03125f;       // 1/sqrt(N)
    const float betaD = 1.f / 12.f;     // BETA / D
    const size_t LSTRIDE = (size_t)6144 * 1024;       // per-layer Wt elements
    const int NPADV = (VV + 127) & ~127;              // 50304
    const int TROUT = 262;              // outW tiles per slot (48 slots * 262 = 12576)

    // Acts: x f32 4MB | h 2MB | mid 2MB | qh 2MB | kh 2MB | vt 2MB | ob 2MB = 16MB
    char* p = (char*)d_ws;
    float* x   = (float*)p;   p += (size_t)4 << 20;
    u16*   h   = (u16*)p;     p += (size_t)2 << 20;
    u16*   mid = (u16*)p;     p += (size_t)2 << 20;
    u16*   qh  = (u16*)p;     p += (size_t)2 << 20;
    u16*   kh  = (u16*)p;     p += (size_t)2 << 20;
    u16*   vt  = (u16*)p;     p += (size_t)2 << 20;
    u16*   ob  = (u16*)p;     p += (size_t)2 << 20;

    bool big = ws_size >= ((size_t)264 << 20);
    u16* WtAll = (u16*)p;
    u16* WtL;
    if (big) WtL = WtAll + (size_t)12 * LSTRIDE;
    else     WtL = WtAll + LSTRIDE;

    TrPack EMPTY{};   // zero-initialized: all ntiles = 0

    embed_k<<<1024, 256, 0, stream>>>(tok, emb, pos, x);
    if (big) {
        // upfront: layer-0 weights only (outW + layers 1..11 absorbed into GEMMs)
        transpose5_k<<<dim3(32, 16, 5), 256, 0, stream>>>(qkW, vW, oW, W1, W2,
                WtAll, 0, LSTRIDE);
    }

    for (int l = 0; l < NL; ++l) {
        const u16* WtB = big ? WtAll + (size_t)l * LSTRIDE : WtAll;
        ln_k<1><<<1024, 256, 0, stream>>>(x, h, ln1s + l * NN, ln1b + l * NN);
        if (!big) {
            transpose5_k<<<dim3(32, 16, 5), 256, 0, stream>>>(qkW, vW, oW, W1, W2,
                    WtAll, l, 0);
        }
        bool nx = big && (l + 1 < NL);
        u16* WtN = WtAll + (size_t)(l + 1) * LSTRIDE;
        int slot = l * 4;

        // QKV (768 gemm) + filler: qk(l+1) 512 tiles + outW slot
        {
            TrPack P = EMPTY; int ntr = 0;
            if (nx) { P.j[0] = {qkW + (size_t)(l + 1) * NN * 2048, WtN, 2048, 2048, 512, 0}; ntr += 512; }
            if (big) { P.j[1] = {outW, WtL, VV, VV, TROUT, (slot + 0) * TROUT}; ntr += TROUT; }
            gemm_k<32,128,5><<<768 + ntr, 256, 0, stream>>>(h, WtB, vt, qh, kh,
                    nullptr, qns + l * HD, qnb + l * HD, kns + l * HD, knb + l * HD,
                    NN, 0, 0, 0, inv32, 0.f, 768, 24, P);
        }
        attn_k<<<dim3(8, 32), 512, 0, stream>>>(qh, kh, vt, ob);
        // oproj (512 gemm) + filler: v(l+1) + o(l+1) + outW slot
        {
            TrPack P = EMPTY; int ntr = 0;
            if (nx) {
                P.j[0] = {vW + (size_t)(l + 1) * NN * NN, WtN + (size_t)2048 * 1024, 1024, 1024, 256, 0};
                P.j[1] = {oW + (size_t)(l + 1) * NN * NN, WtN + (size_t)3072 * 1024, 1024, 1024, 256, 0};
                ntr += 512;
            }
            if (big) { P.j[2] = {outW, WtL, VV, VV, TROUT, (slot + 1) * TROUT}; ntr += TROUT; }
            gemm_k<32,64,1><<<512 + ntr, 256, 0, stream>>>(ob, WtB + (size_t)3072 * 1024,
                    x, nullptr, nullptr, nullptr, nullptr, nullptr, nullptr, nullptr,
                    NN, NN, 0, 0, inv32, betaD, 512, 16, P);
        }
        ln_k<1><<<1024, 256, 0, stream>>>(x, h, ln2s + l * NN, ln2b + l * NN);
        // mlp1 (512 gemm) + filler: W1(l+1) + outW slot
        {
            TrPack P = EMPTY; int ntr = 0;
            if (nx) { P.j[0] = {W1 + (size_t)(l + 1) * NN * NN, WtN + (size_t)4096 * 1024, 1024, 1024, 256, 0}; ntr += 256; }
            if (big) { P.j[1] = {outW, WtL, VV, VV, TROUT, (slot + 2) * TROUT}; ntr += TROUT; }
            gemm_k<32,64,2><<<512 + ntr, 256, 0, stream>>>(h, WtB + (size_t)4096 * 1024,
                    mid, nullptr, nullptr, nullptr, nullptr, nullptr, nullptr, nullptr,
                    NN, NN, 0, 0, inv32, 0.f, 512, 16, P);
        }
        // mlp2 (512 gemm) + filler: W2(l+1) + outW slot
        {
            TrPack P = EMPTY; int ntr = 0;
            if (nx) { P.j[0] = {W2 + (size_t)(l + 1) * NN * NN, WtN + (size_t)5120 * 1024, 1024, 1024, 256, 0}; ntr += 256; }
            if (big) { P.j[1] = {outW, WtL, VV, VV, TROUT, (slot + 3) * TROUT}; ntr += TROUT; }
            gemm_k<32,64,1><<<512 + ntr, 256, 0, stream>>>(mid, WtB + (size_t)5120 * 1024,
                    x, nullptr, nullptr, nullptr, nullptr, nullptr, nullptr, nullptr,
                    NN, NN, 0, 0, inv32, betaD, 512, 16, P);
        }
    }
    ln_k<0><<<1024, 256, 0, stream>>>(x, h, lnfs, lnfb);

    if (big) {
        gemm_k<128,128,3,1><<<dim3(NPADV / 128 * 8), 256, 0, stream>>>(h, WtL, out,
                nullptr, nullptr, outb, nullptr, nullptr, nullptr, nullptr,
                NN, VV, 0, VV, inv32, 0.f, NPADV / 128 * 8, 0, EMPTY);
    } else {
        for (int c0 = 0; c0 < VV; c0 += 16384) {
            int cn = VV - c0; if (cn > 16384) cn = 16384;
            int npad = (cn + 127) & ~127;
            transpose_k<<<dim3(npad / 64, 16), 256, 0, stream>>>(outW + c0, WtL, cn, VV, NN);
            gemm_k<128,128,3,1><<<dim3(npad / 128 * 8), 256, 0, stream>>>(h, WtL, out,
                    nullptr, nullptr, outb, nullptr, nullptr, nullptr, nullptr,
                    NN, VV, c0, VV, inv32, 0.f, npad / 128 * 8, 0, EMPTY);
        }
    }
}

// Round 18
// 1138.551 us; speedup vs baseline: 2.4379x; 1.0402x over previous
//
#include <hip/hip_runtime.h>
#include <hip/hip_bf16.h>

// Model constants
#define TT 512
#define NN 1024
#define NH 16
#define HD 64
#define NL 12
#define VV 50257

typedef unsigned short u16;
typedef short bf16x8 __attribute__((ext_vector_type(8)));
typedef float f32x4 __attribute__((ext_vector_type(4)));

struct TrJob { const float* src; u16* dst; int ncols; int ldw; int ntiles; int tbase; };
struct TrPack { TrJob j[3]; };

__device__ __forceinline__ float gelu_f(float x) {
    float x3 = x * x * x;
    return 0.5f * x * (1.0f + tanhf(0.7978845608028654f * (x + 0.044715f * x3)));
}

// fp32 -> bf16 RNE (finite inputs only)
__device__ __forceinline__ u16 f2b(float f) {
    unsigned int u = __float_as_uint(f);
    return (u16)((u + 0x7FFFu + ((u >> 16) & 1u)) >> 16);
}

// async global->LDS, 16B per lane; LDS dest is wave-uniform base + lane*16
__device__ __forceinline__ void gload16(const void* g, void* l) {
    __builtin_amdgcn_global_load_lds(
        (const __attribute__((address_space(1))) unsigned int*)g,
        (__attribute__((address_space(3))) unsigned int*)l,
        16, 0, 0);
}

// x[row,:] = 1024*emb[tok[row],:] + 32*pos[t,:]
__global__ __launch_bounds__(256) void embed_k(const int* __restrict__ tok,
        const float* __restrict__ emb, const float* __restrict__ pos,
        float* __restrict__ x) {
    int row = blockIdx.x;
    int t = row & (TT - 1);
    int tk = tok[row];
    int c = threadIdx.x * 4;
    float4 e = *reinterpret_cast<const float4*>(emb + (size_t)tk * NN + c);
    float4 p = *reinterpret_cast<const float4*>(pos + (size_t)t * NN + c);
    float4 o;
    o.x = 1024.f * e.x + 32.f * p.x;
    o.y = 1024.f * e.y + 32.f * p.y;
    o.z = 1024.f * e.z + 32.f * p.z;
    o.w = 1024.f * e.w + 32.f * p.w;
    *reinterpret_cast<float4*>(x + (size_t)row * NN + c) = o;
}

// Row LayerNorm over N=1024 (+ optional gelu), bf16 output
template<int ACT>
__global__ __launch_bounds__(256) void ln_k(const float* __restrict__ in,
        u16* __restrict__ out, const float* __restrict__ sc, const float* __restrict__ bi) {
    int row = blockIdx.x;
    const float* r = in + (size_t)row * NN;
    int tid = threadIdx.x;
    float v[4]; float s1 = 0.f, s2 = 0.f;
    #pragma unroll
    for (int i = 0; i < 4; ++i) { v[i] = r[tid + i * 256]; s1 += v[i]; s2 += v[i] * v[i]; }
    #pragma unroll
    for (int off = 32; off > 0; off >>= 1) { s1 += __shfl_xor(s1, off); s2 += __shfl_xor(s2, off); }
    __shared__ float red[8];
    __shared__ float st[2];
    int wid = tid >> 6;
    if ((tid & 63) == 0) { red[wid] = s1; red[4 + wid] = s2; }
    __syncthreads();
    if (tid == 0) {
        float a = red[0] + red[1] + red[2] + red[3];
        float b = red[4] + red[5] + red[6] + red[7];
        float mu = a * (1.f / NN);
        float var = b * (1.f / NN) - mu * mu;
        st[0] = mu; st[1] = rsqrtf(var + 1e-6f);
    }
    __syncthreads();
    float mu = st[0], rs = st[1];
    u16* o = out + (size_t)row * NN;
    #pragma unroll
    for (int i = 0; i < 4; ++i) {
        int c = tid + i * 256;
        float y = (v[i] - mu) * rs * sc[c] + bi[c];
        if (ACT) y = gelu_f(y);
        o[c] = f2b(y);
    }
}

// Per-layer weight transpose (upfront, layer l0 only): z selects which of 5.
__global__ __launch_bounds__(256) void transpose5_k(const float* __restrict__ qkW,
        const float* __restrict__ vW, const float* __restrict__ oW,
        const float* __restrict__ W1, const float* __restrict__ W2,
        u16* __restrict__ Wt, int l0, size_t lstride) {
    int z = blockIdx.z + l0 * 5;
    int l = z / 5, which = z - l * 5;
    const float* W; int Ncols; size_t doff;
    switch (which) {
      case 0:  W = qkW + (size_t)l * NN * 2048; Ncols = 2048; doff = 0; break;
      case 1:  W = vW + (size_t)l * NN * NN;  Ncols = 1024; doff = (size_t)2048 * 1024; break;
      case 2:  W = oW + (size_t)l * NN * NN;  Ncols = 1024; doff = (size_t)3072 * 1024; break;
      case 3:  W = W1 + (size_t)l * NN * NN;  Ncols = 1024; doff = (size_t)4096 * 1024; break;
      default: W = W2 + (size_t)l * NN * NN;  Ncols = 1024; doff = (size_t)5120 * 1024; break;
    }
    int n0 = blockIdx.x * 64;
    if (n0 >= Ncols) return;
    int k0 = blockIdx.y * 64;
    u16* dst = Wt + (size_t)l * lstride + doff;
    __shared__ float t[64][65];
    int tid = threadIdx.x;
    #pragma unroll
    for (int j = 0; j < 4; ++j) {
        int e = tid + j * 256;
        int kr = e >> 4, nc = (e & 15) * 4;
        float4 v = *reinterpret_cast<const float4*>(W + (size_t)(k0 + kr) * Ncols + n0 + nc);
        t[kr][nc + 0] = v.x; t[kr][nc + 1] = v.y; t[kr][nc + 2] = v.z; t[kr][nc + 3] = v.w;
    }
    __syncthreads();
    #pragma unroll
    for (int j = 0; j < 4; ++j) {
        int e = tid + j * 256;
        int nr = e >> 4, kc = (e & 15) * 4;
        ushort4 o;
        o.x = f2b(t[kc + 0][nr]);
        o.y = f2b(t[kc + 1][nr]);
        o.z = f2b(t[kc + 2][nr]);
        o.w = f2b(t[kc + 3][nr]);
        *reinterpret_cast<ushort4*>(dst + (size_t)(n0 + nr) * 1024 + k0 + kc) = o;
    }
}

// Guarded single transpose (small-path fallback): fp32 [K][Ncols] -> bf16 [Npad][K]
__global__ __launch_bounds__(256) void transpose_k(const float* __restrict__ W,
        u16* __restrict__ Wt, int Ncols, int ldW, int K) {
    __shared__ float t[64][65];
    int n0 = blockIdx.x * 64, k0 = blockIdx.y * 64;
    int tid = threadIdx.x;
    #pragma unroll
    for (int j = 0; j < 4; ++j) {
        int e = tid + j * 256;
        int kr = e >> 4, nc = (e & 15) * 4;
        int n = n0 + nc;
        float4 v = {0.f, 0.f, 0.f, 0.f};
        if (n + 3 < Ncols) {
            v = *reinterpret_cast<const float4*>(W + (size_t)(k0 + kr) * ldW + n);
        } else {
            if (n + 0 < Ncols) v.x = W[(size_t)(k0 + kr) * ldW + n + 0];
            if (n + 1 < Ncols) v.y = W[(size_t)(k0 + kr) * ldW + n + 1];
            if (n + 2 < Ncols) v.z = W[(size_t)(k0 + kr) * ldW + n + 2];
        }
        t[kr][nc + 0] = v.x; t[kr][nc + 1] = v.y; t[kr][nc + 2] = v.z; t[kr][nc + 3] = v.w;
    }
    __syncthreads();
    #pragma unroll
    for (int j = 0; j < 4; ++j) {
        int e = tid + j * 256;
        int nr = e >> 4, kc = (e & 15) * 4;
        ushort4 o;
        o.x = f2b(t[kc + 0][nr]);
        o.y = f2b(t[kc + 1][nr]);
        o.z = f2b(t[kc + 2][nr]);
        o.w = f2b(t[kc + 3][nr]);
        *reinterpret_cast<ushort4*>(Wt + (size_t)(n0 + nr) * K + k0 + kc) = o;
    }
}

// swizzled LDS fragment read: row r, logical 16B chunk c
__device__ __forceinline__ bf16x8 ldsfrag(const u16* base, int r, int c) {
    int off = r * 64 + ((c ^ (r & 7)) << 3);
    return *reinterpret_cast<const bf16x8*>(base + off);
}

// MFMA GEMM, TMxTN tile, BK=64*KU, SINGLE-buffer LDS (m97 structure).
// KU: K-slices staged per barrier (2 halves barrier count for latency-bound
// small GEMMs; logits keeps KU=1 to preserve its 5-blocks/CU occupancy).
// 1D grid: blocks [0,nGemm) do GEMM; blocks [nGemm,..) run absorbed 64x64
// weight-transpose tiles from TrPack (next layer / outW; stream order = safe).
// XCDMAP=1: logits mapping (8 m-tiles of a B-panel on SAME XCD), no filler.
// EPI 1/2 SWAPPED mfma operands -> float4/ushort4 epilogue. EPI 3 unswapped.
// EPI 5: fused QKV (unswapped): per-head LN -> qh/kh; V^T -> vt.
template<int TM, int TN, int EPI, int XCDMAP = 0, int KU = 1>
__global__ __launch_bounds__(256) void gemm_k(const u16* __restrict__ A,
        const u16* __restrict__ Bt, void* __restrict__ C,
        void* __restrict__ C2, void* __restrict__ C3,
        const float* __restrict__ bias,
        const float* __restrict__ qs, const float* __restrict__ qb,
        const float* __restrict__ ks, const float* __restrict__ kb,
        int K, int ldC, int coff, int cmax, float scale, float rbeta,
        int nGemm, int NX, TrPack trp) {
    constexpr int MF = TM / 32, NF = TN / 32;     // frags per wave
    constexpr int IA = TM / 8, IB = TN / 8;       // 1KB staging issues per slice
    constexpr bool SW = (EPI == 1 || EPI == 2);   // swapped operand order
    constexpr int GB = (TM + TN) * 128 * KU;      // gemm LDS bytes
    constexpr int SB = (GB > 16640) ? GB : 16640; // union with transpose tile
    __shared__ __align__(16) char smem[SB];
    u16* As = (u16*)smem;                         // [KU][TM*64]
    u16* Bs = As + (size_t)KU * TM * 64;          // [KU][TN*64]
    int tid = threadIdx.x;
    int lam = tid & 63, w = tid >> 6;
    int m0, n0;
    if (XCDMAP) {
        int i = blockIdx.x;
        int per = gridDim.x >> 3;          // jobs per XCD
        int j = (i & 7) * per + (i >> 3);  // xcd-grouped job id
        m0 = (j & 7) * TM;                 // 8 m-tiles cycle fastest
        n0 = (j >> 3) * TN;                // consecutive panels per XCD
    } else {
        int id = blockIdx.x;
        if (id >= nGemm) {
            // absorbed transpose tile
            int ex = id - nGemm;
            const float* src = nullptr; u16* dst = nullptr;
            int ncols = 0, ldw = 0, tno = 0;
            #pragma unroll
            for (int jj = 0; jj < 3; ++jj) {
                int nt = trp.j[jj].ntiles;
                if (src == nullptr && ex < nt) {
                    src = trp.j[jj].src; dst = trp.j[jj].dst;
                    ncols = trp.j[jj].ncols; ldw = trp.j[jj].ldw;
                    tno = trp.j[jj].tbase + ex;
                }
                if (src == nullptr) ex -= nt;
            }
            if (src) {
                int ntx = (ncols + 63) >> 6;
                int tn0 = (tno % ntx) * 64, tk0 = (tno / ntx) * 64;
                float (*t)[65] = (float (*)[65])smem;
                #pragma unroll
                for (int j = 0; j < 4; ++j) {
                    int e = tid + j * 256;
                    int kr = e >> 4, nc = (e & 15) * 4;
                    int n = tn0 + nc;
                    float4 v = {0.f, 0.f, 0.f, 0.f};
                    if (n + 3 < ncols) {
                        v = *reinterpret_cast<const float4*>(src + (size_t)(tk0 + kr) * ldw + n);
                    } else {
                        if (n + 0 < ncols) v.x = src[(size_t)(tk0 + kr) * ldw + n + 0];
                        if (n + 1 < ncols) v.y = src[(size_t)(tk0 + kr) * ldw + n + 1];
                        if (n + 2 < ncols) v.z = src[(size_t)(tk0 + kr) * ldw + n + 2];
                    }
                    t[kr][nc + 0] = v.x; t[kr][nc + 1] = v.y;
                    t[kr][nc + 2] = v.z; t[kr][nc + 3] = v.w;
                }
                __syncthreads();
                #pragma unroll
                for (int j = 0; j < 4; ++j) {
                    int e = tid + j * 256;
                    int nr = e >> 4, kc = (e & 15) * 4;
                    ushort4 o;
                    o.x = f2b(t[kc + 0][nr]);
                    o.y = f2b(t[kc + 1][nr]);
                    o.z = f2b(t[kc + 2][nr]);
                    o.w = f2b(t[kc + 3][nr]);
                    *reinterpret_cast<ushort4*>(dst + (size_t)(tn0 + nr) * 1024 + tk0 + kc) = o;
                }
            }
            return;
        }
        m0 = (id / NX) * TM;
        n0 = (id % NX) * TN;
    }
    int lr = lam >> 3;              // row-in-8 within a 1KB issue
    int lc = (lam & 7) ^ lr;        // inverse-swizzled logical chunk
    const u16* Abase = A + (size_t)m0 * K;
    const u16* Bbase = Bt + (size_t)n0 * K;
    int wr = (w >> 1) * (TM / 2), wc = (w & 1) * (TN / 2);
    int fr = lam & 15, fg = lam >> 4;
    f32x4 acc[MF][NF];
    #pragma unroll
    for (int i = 0; i < MF; ++i)
        #pragma unroll
        for (int j = 0; j < NF; ++j) acc[i][j] = (f32x4)0.0f;

    for (int k0 = 0; k0 < K; k0 += 64 * KU) {
        #pragma unroll
        for (int u = 0; u < KU; ++u) {
            #pragma unroll
            for (int i = 0; i < IA / 4; ++i) {
                int q = w * (IA / 4) + i;
                int r = q * 8 + lr;
                gload16(Abase + (size_t)r * K + k0 + u * 64 + lc * 8,
                        (char*)(As + (size_t)u * TM * 64) + q * 1024);
            }
            #pragma unroll
            for (int i = 0; i < IB / 4; ++i) {
                int q = w * (IB / 4) + i;
                int r = q * 8 + lr;
                gload16(Bbase + (size_t)r * K + k0 + u * 64 + lc * 8,
                        (char*)(Bs + (size_t)u * TN * 64) + q * 1024);
            }
        }
        __syncthreads();                   // drains vmcnt(0) + barrier
        #pragma unroll
        for (int u = 0; u < KU; ++u) {
            const u16* Au = As + (size_t)u * TM * 64;
            const u16* Bu = Bs + (size_t)u * TN * 64;
            #pragma unroll
            for (int s = 0; s < 2; ++s) {
                bf16x8 af[MF], bfv[NF];
                #pragma unroll
                for (int m = 0; m < MF; ++m) af[m] = ldsfrag(Au, wr + m * 16 + fr, s * 4 + fg);
                #pragma unroll
                for (int n = 0; n < NF; ++n) bfv[n] = ldsfrag(Bu, wc + n * 16 + fr, s * 4 + fg);
                #pragma unroll
                for (int m = 0; m < MF; ++m)
                    #pragma unroll
                    for (int n = 0; n < NF; ++n) {
                        if (SW)
                            acc[m][n] = __builtin_amdgcn_mfma_f32_16x16x32_bf16(bfv[n], af[m], acc[m][n], 0, 0, 0);
                        else
                            acc[m][n] = __builtin_amdgcn_mfma_f32_16x16x32_bf16(af[m], bfv[n], acc[m][n], 0, 0, 0);
                    }
            }
        }
        if (k0 + 64 * KU < K) __syncthreads();  // protect LDS overwrite
    }

    if constexpr (SW) {
        // Swapped: C row = m0+wr+m*16+fr, cols = n0+wc+n*16+4*fg+{0..3}
        #pragma unroll
        for (int m = 0; m < MF; ++m) {
            int row = m0 + wr + m * 16 + fr;
            #pragma unroll
            for (int n = 0; n < NF; ++n) {
                int colb = n0 + wc + n * 16 + 4 * fg;
                f32x4 a4 = acc[m][n];
                if (EPI == 1) {
                    float* p = (float*)C + (size_t)row * ldC + colb;
                    float4 x4 = *reinterpret_cast<const float4*>(p);
                    float4 o4;
                    o4.x = x4.x + rbeta * (a4[0] * scale);
                    o4.y = x4.y + rbeta * (a4[1] * scale);
                    o4.z = x4.z + rbeta * (a4[2] * scale);
                    o4.w = x4.w + rbeta * (a4[3] * scale);
                    *reinterpret_cast<float4*>(p) = o4;
                } else {
                    ushort4 o4;
                    o4.x = f2b(gelu_f(a4[0] * scale));
                    o4.y = f2b(gelu_f(a4[1] * scale));
                    o4.z = f2b(gelu_f(a4[2] * scale));
                    o4.w = f2b(gelu_f(a4[3] * scale));
                    *reinterpret_cast<ushort4*>((u16*)C + (size_t)row * ldC + colb) = o4;
                }
            }
        }
        return;
    }

    // Unswapped: col = lane&15 (n side), row = (lane>>4)*4+reg (m side)
    if constexpr (EPI == 3) {
        #pragma unroll
        for (int m = 0; m < MF; ++m) {
            #pragma unroll
            for (int n = 0; n < NF; ++n) {
                int ncol = n0 + wc + n * 16 + fr;
                int mrow = m0 + wr + m * 16 + 4 * fg;
                #pragma unroll
                for (int reg = 0; reg < 4; ++reg) {
                    int row = mrow + reg;
                    int gc = coff + ncol;
                    if (gc < cmax)
                        ((float*)C)[(size_t)row * ldC + gc] = (acc[m][n][reg] + bias[gc]) * scale;
                }
            }
        }
        return;
    }
    // EPI == 5
    if (n0 < 2048) {
        int sq = wc >> 6;                    // 0 = q half, 1 = k half
        int head = n0 >> 7;
        const float* scp = sq ? ks : qs;
        const float* bip = sq ? kb : qb;
        u16* dst = (u16*)(sq ? C3 : C2);
        float scv[NF], biv[NF];
        #pragma unroll
        for (int n = 0; n < NF; ++n) { scv[n] = scp[n * 16 + fr]; biv[n] = bip[n * 16 + fr]; }
        #pragma unroll
        for (int m = 0; m < MF; ++m) {
            #pragma unroll
            for (int reg = 0; reg < 4; ++reg) {
                float v[NF]; float s1 = 0.f, s2 = 0.f;
                #pragma unroll
                for (int n = 0; n < NF; ++n) {
                    v[n] = acc[m][n][reg] * scale;
                    s1 += v[n]; s2 += v[n] * v[n];
                }
                #pragma unroll
                for (int off = 1; off < 16; off <<= 1) {
                    s1 += __shfl_xor(s1, off);
                    s2 += __shfl_xor(s2, off);
                }
                float mu = s1 * (1.f / 64.f);
                float var = s2 * (1.f / 64.f) - mu * mu;
                float rs = rsqrtf(var + 1e-6f);
                int row = m0 + wr + m * 16 + 4 * fg + reg;
                int bb = row >> 9, t = row & (TT - 1);
                size_t base = ((size_t)(bb * NH + head) * TT + t) * HD;
                #pragma unroll
                for (int n = 0; n < NF; ++n)
                    dst[base + n * 16 + fr] = f2b((v[n] - mu) * rs * scv[n] + biv[n]);
            }
        }
    } else {
        #pragma unroll
        for (int m = 0; m < MF; ++m) {
            int row0 = m0 + wr + m * 16 + 4 * fg;
            int bb = row0 >> 9, t0 = row0 & (TT - 1);
            #pragma unroll
            for (int n = 0; n < NF; ++n) {
                int colv = n0 - 2048 + wc + n * 16 + fr;
                int hh = colv >> 6, dd = colv & 63;
                ushort4 o4;
                o4.x = f2b(acc[m][n][0] * scale);
                o4.y = f2b(acc[m][n][1] * scale);
                o4.z = f2b(acc[m][n][2] * scale);
                o4.w = f2b(acc[m][n][3] * scale);
                *reinterpret_cast<ushort4*>((u16*)C +
                    (((size_t)(bb * NH + hh) * HD + dd) * TT + t0)) = o4;
            }
        }
    }
}

// Fused flash attention, k-split: per (qt, bh) block, 8 waves (512 thr).
__global__ __launch_bounds__(512) void attn_k(const u16* __restrict__ qh,
        const u16* __restrict__ kh, const u16* __restrict__ vt,
        u16* __restrict__ ob) {
    int qt = blockIdx.x, bh = blockIdx.y;
    int b = bh >> 4, hh = bh & 15;
    int tid = threadIdx.x;
    int w = tid >> 6, lam = tid & 63;
    int sub = w & 3, half = w >> 2;
    int fr = lam & 15, fg = lam >> 4;
    __shared__ __align__(16) u16 ps[8][16 * 64];   // per-wave P tile, XOR-swizzled
    __shared__ __align__(16) f32x4 comb[4][64][5]; // half-0 partials: oacc[4] + rsum
    u16* pw = ps[w];
    const u16* qbase = qh + ((size_t)bh * TT + qt * 64 + sub * 16) * HD;
    bf16x8 af0 = *reinterpret_cast<const bf16x8*>(qbase + (size_t)fr * HD + fg * 8);
    bf16x8 af1 = *reinterpret_cast<const bf16x8*>(qbase + (size_t)fr * HD + 32 + fg * 8);
    f32x4 oacc[4];
    #pragma unroll
    for (int n = 0; n < 4; ++n) oacc[n] = (f32x4)0.0f;
    float rsum[4] = {0.f, 0.f, 0.f, 0.f};
    const u16* vbh = vt + (size_t)bh * HD * TT;
    for (int kt = half; kt <= qt; kt += 2) {
        const u16* kbase = kh + ((size_t)bh * TT + kt * 64) * HD;
        bool diag = (kt == qt);
        #pragma unroll
        for (int n = 0; n < 4; ++n) {
            bf16x8 b0 = *reinterpret_cast<const bf16x8*>(kbase + (size_t)(n * 16 + fr) * HD + fg * 8);
            bf16x8 b1 = *reinterpret_cast<const bf16x8*>(kbase + (size_t)(n * 16 + fr) * HD + 32 + fg * 8);
            f32x4 s = (f32x4)0.0f;
            s = __builtin_amdgcn_mfma_f32_16x16x32_bf16(af0, b0, s, 0, 0, 0);
            s = __builtin_amdgcn_mfma_f32_16x16x32_bf16(af1, b1, s, 0, 0, 0);
            #pragma unroll
            for (int reg = 0; reg < 4; ++reg) {
                int row = fg * 4 + reg;            // q-local within sub-tile
                int col = n * 16 + fr;             // k-local (0..63)
                float p = 0.f;
                if (!diag || col <= (sub * 16 + row)) p = __expf(s[reg] * (1.f / 64.f));
                rsum[reg] += p;
                int chunk = col >> 3;
                int off = row * 128 + (((chunk ^ (row & 7)) << 4) | ((col & 7) << 1));
                *reinterpret_cast<u16*>((char*)pw + off) = f2b(p);
            }
        }
        bf16x8 pa0, pa1;
        {
            int c0 = 0 * 4 + fg, c1 = 1 * 4 + fg;
            pa0 = *reinterpret_cast<const bf16x8*>((char*)pw + fr * 128 + ((c0 ^ (fr & 7)) << 4));
            pa1 = *reinterpret_cast<const bf16x8*>((char*)pw + fr * 128 + ((c1 ^ (fr & 7)) << 4));
        }
        #pragma unroll
        for (int n = 0; n < 4; ++n) {
            const u16* vb = vbh + (size_t)(n * 16 + fr) * TT + kt * 64;
            bf16x8 v0 = *reinterpret_cast<const bf16x8*>(vb + fg * 8);
            bf16x8 v1 = *reinterpret_cast<const bf16x8*>(vb + 32 + fg * 8);
            oacc[n] = __builtin_amdgcn_mfma_f32_16x16x32_bf16(pa0, v0, oacc[n], 0, 0, 0);
            oacc[n] = __builtin_amdgcn_mfma_f32_16x16x32_bf16(pa1, v1, oacc[n], 0, 0, 0);
        }
    }
    if (half == 0) {
        #pragma unroll
        for (int n = 0; n < 4; ++n) comb[sub][lam][n] = oacc[n];
        f32x4 r4 = {rsum[0], rsum[1], rsum[2], rsum[3]};
        comb[sub][lam][4] = r4;
    }
    __syncthreads();
    if (half == 1) {
        #pragma unroll
        for (int n = 0; n < 4; ++n) oacc[n] += comb[sub][lam][n];
        f32x4 r4 = comb[sub][lam][4];
        rsum[0] += r4[0]; rsum[1] += r4[1]; rsum[2] += r4[2]; rsum[3] += r4[3];
        #pragma unroll
        for (int reg = 0; reg < 4; ++reg) {
            float r = rsum[reg];
            r += __shfl_xor(r, 1); r += __shfl_xor(r, 2);
            r += __shfl_xor(r, 4); r += __shfl_xor(r, 8);
            rsum[reg] = 1.f / r;
        }
        int tbase = b * TT + qt * 64 + sub * 16 + fg * 4;
        #pragma unroll
        for (int n = 0; n < 4; ++n) {
            int dcol = hh * 64 + n * 16 + fr;
            #pragma unroll
            for (int reg = 0; reg < 4; ++reg)
                ob[(size_t)(tbase + reg) * NN + dcol] = f2b(oacc[n][reg] * rsum[reg]);
        }
    }
}

extern "C" void kernel_launch(void* const* d_in, const int* in_sizes, int n_in,
                              void* d_out, int out_size, void* d_ws, size_t ws_size,
                              hipStream_t stream) {
    (void)in_sizes; (void)n_in; (void)out_size;
    const int*   tok  = (const int*)d_in[0];
    const float* emb  = (const float*)d_in[1];
    const float* pos  = (const float*)d_in[2];
    const float* ln1s = (const float*)d_in[3];
    const float* ln1b = (const float*)d_in[4];
    const float* qkW  = (const float*)d_in[5];
    const float* vW   = (const float*)d_in[6];
    const float* oW   = (const float*)d_in[7];
    const float* qns  = (const float*)d_in[8];
    const float* qnb  = (const float*)d_in[9];
    const float* kns  = (const float*)d_in[10];
    const float* knb  = (const float*)d_in[11];
    const float* ln2s = (const float*)d_in[12];
    const float* ln2b = (const float*)d_in[13];
    const float* W1   = (const float*)d_in[14];
    const float* W2   = (const float*)d_in[15];
    const float* lnfs = (const float*)d_in[16];
    const float* lnfb = (const float*)d_in[17];
    const float* outW = (const float*)d_in[18];
    const float* outb = (const float*)d_in[19];
    float* out = (float*)d_out;

    const float inv32 = 0.03125f;       // 1/sqrt(N)
    const float betaD = 1.f / 12.f;     // BETA / D
    const size_t LSTRIDE = (size_t)6144 * 1024;       // per-layer Wt elements
    const int NPADV = (VV + 127) & ~127;              // 50304
    const int TROUT = 262;              // outW tiles per slot (48 slots * 262 = 12576)

    // Acts: x f32 4MB | h 2MB | mid 2MB | qh 2MB | kh 2MB | vt 2MB | ob 2MB = 16MB
    char* p = (char*)d_ws;
    float* x   = (float*)p;   p += (size_t)4 << 20;
    u16*   h   = (u16*)p;     p += (size_t)2 << 20;
    u16*   mid = (u16*)p;     p += (size_t)2 << 20;
    u16*   qh  = (u16*)p;     p += (size_t)2 << 20;
    u16*   kh  = (u16*)p;     p += (size_t)2 << 20;
    u16*   vt  = (u16*)p;     p += (size_t)2 << 20;
    u16*   ob  = (u16*)p;     p += (size_t)2 << 20;

    bool big = ws_size >= ((size_t)264 << 20);
    u16* WtAll = (u16*)p;
    u16* WtL;
    if (big) WtL = WtAll + (size_t)12 * LSTRIDE;
    else     WtL = WtAll + LSTRIDE;

    TrPack EMPTY{};   // zero-initialized: all ntiles = 0

    embed_k<<<1024, 256, 0, stream>>>(tok, emb, pos, x);
    if (big) {
        // upfront: layer-0 weights only (outW + layers 1..11 absorbed into GEMMs)
        transpose5_k<<<dim3(32, 16, 5), 256, 0, stream>>>(qkW, vW, oW, W1, W2,
                WtAll, 0, LSTRIDE);
    }

    for (int l = 0; l < NL; ++l) {
        const u16* WtB = big ? WtAll + (size_t)l * LSTRIDE : WtAll;
        ln_k<1><<<1024, 256, 0, stream>>>(x, h, ln1s + l * NN, ln1b + l * NN);
        if (!big) {
            transpose5_k<<<dim3(32, 16, 5), 256, 0, stream>>>(qkW, vW, oW, W1, W2,
                    WtAll, l, 0);
        }
        bool nx = big && (l + 1 < NL);
        u16* WtN = WtAll + (size_t)(l + 1) * LSTRIDE;
        int slot = l * 4;

        // QKV (768 gemm, KU=2) + filler: qk(l+1) 512 tiles + outW slot
        {
            TrPack P = EMPTY; int ntr = 0;
            if (nx) { P.j[0] = {qkW + (size_t)(l + 1) * NN * 2048, WtN, 2048, 2048, 512, 0}; ntr += 512; }
            if (big) { P.j[1] = {outW, WtL, VV, VV, TROUT, (slot + 0) * TROUT}; ntr += TROUT; }
            gemm_k<32,128,5,0,2><<<768 + ntr, 256, 0, stream>>>(h, WtB, vt, qh, kh,
                    nullptr, qns + l * HD, qnb + l * HD, kns + l * HD, knb + l * HD,
                    NN, 0, 0, 0, inv32, 0.f, 768, 24, P);
        }
        attn_k<<<dim3(8, 32), 512, 0, stream>>>(qh, kh, vt, ob);
        // oproj (512 gemm, KU=2) + filler: v(l+1) + o(l+1) + outW slot
        {
            TrPack P = EMPTY; int ntr = 0;
            if (nx) {
                P.j[0] = {vW + (size_t)(l + 1) * NN * NN, WtN + (size_t)2048 * 1024, 1024, 1024, 256, 0};
                P.j[1] = {oW + (size_t)(l + 1) * NN * NN, WtN + (size_t)3072 * 1024, 1024, 1024, 256, 0};
                ntr += 512;
            }
            if (big) { P.j[2] = {outW, WtL, VV, VV, TROUT, (slot + 1) * TROUT}; ntr += TROUT; }
            gemm_k<32,64,1,0,2><<<512 + ntr, 256, 0, stream>>>(ob, WtB + (size_t)3072 * 1024,
                    x, nullptr, nullptr, nullptr, nullptr, nullptr, nullptr, nullptr,
                    NN, NN, 0, 0, inv32, betaD, 512, 16, P);
        }
        ln_k<1><<<1024, 256, 0, stream>>>(x, h, ln2s + l * NN, ln2b + l * NN);
        // mlp1 (512 gemm, KU=2) + filler: W1(l+1) + outW slot
        {
            TrPack P = EMPTY; int ntr = 0;
            if (nx) { P.j[0] = {W1 + (size_t)(l + 1) * NN * NN, WtN + (size_t)4096 * 1024, 1024, 1024, 256, 0}; ntr += 256; }
            if (big) { P.j[1] = {outW, WtL, VV, VV, TROUT, (slot + 2) * TROUT}; ntr += TROUT; }
            gemm_k<32,64,2,0,2><<<512 + ntr, 256, 0, stream>>>(h, WtB + (size_t)4096 * 1024,
                    mid, nullptr, nullptr, nullptr, nullptr, nullptr, nullptr, nullptr,
                    NN, NN, 0, 0, inv32, 0.f, 512, 16, P);
        }
        // mlp2 (512 gemm, KU=2) + filler: W2(l+1) + outW slot
        {
            TrPack P = EMPTY; int ntr = 0;
            if (nx) { P.j[0] = {W2 + (size_t)(l + 1) * NN * NN, WtN + (size_t)5120 * 1024, 1024, 1024, 256, 0}; ntr += 256; }
            if (big) { P.j[1] = {outW, WtL, VV, VV, TROUT, (slot + 3) * TROUT}; ntr += TROUT; }
            gemm_k<32,64,1,0,2><<<512 + ntr, 256, 0, stream>>>(mid, WtB + (size_t)5120 * 1024,
                    x, nullptr, nullptr, nullptr, nullptr, nullptr, nullptr, nullptr,
                    NN, NN, 0, 0, inv32, betaD, 512, 16, P);
        }
    }
    ln_k<0><<<1024, 256, 0, stream>>>(x, h, lnfs, lnfb);

    if (big) {
        gemm_k<128,128,3,1><<<dim3(NPADV / 128 * 8), 256, 0, stream>>>(h, WtL, out,
                nullptr, nullptr, outb, nullptr, nullptr, nullptr, nullptr,
                NN, VV, 0, VV, inv32, 0.f, NPADV / 128 * 8, 0, EMPTY);
    } else {
        for (int c0 = 0; c0 < VV; c0 += 16384) {
            int cn = VV - c0; if (cn > 16384) cn = 16384;
            int npad = (cn + 127) & ~127;
            transpose_k<<<dim3(npad / 64, 16), 256, 0, stream>>>(outW + c0, WtL, cn, VV, NN);
            gemm_k<128,128,3,1><<<dim3(npad / 128 * 8), 256, 0, stream>>>(h, WtL, out,
                    nullptr, nullptr, outb, nullptr, nullptr, nullptr, nullptr,
                    NN, VV, c0, VV, inv32, 0.f, npad / 128 * 8, 0, EMPTY);
        }
    }
}